// Round 3
// baseline (6824.426 us; speedup 1.0000x reference)
//
#include <hip/hip_runtime.h>
#include <math.h>

// CTC prefix beam search, one example per 64-lane wave.
// B=512 examples, T=512 steps, V=96 classes (blank = 95), W=16 beams.
// Numerics replicate XLA:CPU f32 op-for-op (Cephes exp/log inline expansions,
// Goldberg log1p, strict sequential reduce) to match the golden bit-exactly.
#define NBATCH 512
#define TSTEPS 512
#define VCLS   96
#define CCLS   95
#define BWID   16
#define NCAND  1536   // BWID + BWID*CCLS
#define NEGF   (-1e30f)

// ---------------- XLA:CPU-replica transcendentals (no FMA, explicit rounding) ----------------

// Cephes/Eigen-style expf as inlined by XLA:CPU (GenerateVF32Exp).
__device__ __forceinline__ float exp_xla(float x){
    // input clamp (only hit by +/-huge; downstream-insensitive)
    x = fminf(x, 88.3762626647950f);
    x = fmaxf(x, -88.3762626647949f);
    float t = __fadd_rn(__fmul_rn(x, 1.44269504088896341f), 0.5f);
    float m = floorf(t);
    // Cody-Waite: r = x - m*ln2_hi - m*ln2_lo
    float r = __fadd_rn(__fmul_rn(m, -0.693359375f), x);
    r = __fadd_rn(__fmul_rn(m, 2.12194440e-4f), r);
    float y = 1.9875691500E-4f;
    y = __fadd_rn(__fmul_rn(y, r), 1.3981999507E-3f);
    y = __fadd_rn(__fmul_rn(y, r), 8.3334519073E-3f);
    y = __fadd_rn(__fmul_rn(y, r), 4.1665795894E-2f);
    y = __fadd_rn(__fmul_rn(y, r), 1.6666665459E-1f);
    y = __fadd_rn(__fmul_rn(y, r), 5.0000001201E-1f);
    float r2 = __fmul_rn(r, r);
    y = __fadd_rn(__fmul_rn(y, r2), r);
    y = __fadd_rn(y, 1.0f);
    int n = (int)m;                     // m in [-127, 0] for our inputs
    unsigned sb = (unsigned)(n + 127);
    float s = __uint_as_float(sb << 23);   // 2^n (0 if n == -127, like pldexp)
    return __fmul_rn(y, s);
}

// Cephes/Eigen-style logf as inlined by XLA:CPU (GenerateVF32Log). x > 0 normal.
__device__ __forceinline__ float log_xla(float x){
    unsigned bits = __float_as_uint(x);
    int e = (int)(bits >> 23) - 126;
    float m = __uint_as_float((bits & 0x007FFFFFu) | 0x3F000000u);   // [0.5,1)
    if (m < 0.707106781186547524f){
        e -= 1;
        m = __fsub_rn(__fadd_rn(m, m), 1.0f);
    } else {
        m = __fsub_rn(m, 1.0f);
    }
    float z = __fmul_rn(m, m);
    float p = 7.0376836292E-2f;
    p = __fadd_rn(__fmul_rn(p, m), -1.1514610310E-1f);
    p = __fadd_rn(__fmul_rn(p, m),  1.1676998740E-1f);
    p = __fadd_rn(__fmul_rn(p, m), -1.2420140846E-1f);
    p = __fadd_rn(__fmul_rn(p, m),  1.4249322787E-1f);
    p = __fadd_rn(__fmul_rn(p, m), -1.6668057665E-1f);
    p = __fadd_rn(__fmul_rn(p, m),  2.0000714765E-1f);
    p = __fadd_rn(__fmul_rn(p, m), -2.4999993993E-1f);
    p = __fadd_rn(__fmul_rn(p, m),  3.3333331174E-1f);
    // cephes: y = x * ( z * polevl(x) )
    float y = __fmul_rn(m, __fmul_rn(z, p));
    float fe = (float)e;
    y = __fadd_rn(y, __fmul_rn(-2.12194440e-4f, fe));
    y = __fadd_rn(y, __fmul_rn(-0.5f, z));
    float rr = __fadd_rn(m, y);
    rr = __fadd_rn(rr, __fmul_rn(0.693359375f, fe));
    return rr;
}

// XLA ElementalIrEmitter::EmitLog1p (Goldberg): u=1+x; u==1 ? x : log(u)*(x/(u-1))
__device__ __forceinline__ float log1p_xla(float x){
    float u = __fadd_rn(x, 1.0f);
    if (u == 1.0f) return x;
    float lu = log_xla(u);
    float um1 = __fsub_rn(u, 1.0f);
    return __fmul_rn(lu, __fdiv_rn(x, um1));
}

// jnp.logaddexp composition: amax + log1p(exp(-|x-y|)) (no equal-case shortcut; no NaNs here)
__device__ __forceinline__ float logaddexp_x(float x, float y){
    float amax = fmaxf(x, y);
    float d = __fsub_rn(x, y);
    float e = exp_xla(-fabsf(d));
    float l1p = log1p_xla(e);
    return __fadd_rn(amax, l1p);
}

// monotone float -> uint mapping (ascending); no NaN/-0 candidates by construction
__device__ __forceinline__ unsigned ford(float f){
    unsigned u = __float_as_uint(f);
    return (u & 0x80000000u) ? ~u : (u | 0x80000000u);
}

__global__ __launch_bounds__(64)
void ctc_beam(const float* __restrict__ in, float* __restrict__ out)
{
    __shared__ float lp[VCLS];
    __shared__ float evS[VCLS];
    __shared__ float lsumS;
    __shared__ float pbA[BWID], pnbA[BWID], ptotA[BWID], npbA[BWID], staynbA[BWID], stayscA[BWID];
    __shared__ int   lastA[BWID], lenA[BWID];
    __shared__ unsigned long long keys[NCAND];     // 12 KB
    __shared__ unsigned short bp[TSTEPS * BWID];   // 16 KB backpointers: (parent<<8)|(char+1), 0 = stay
    __shared__ float finalsS[BWID];
    __shared__ int bestS;

    const int b    = blockIdx.x;
    const int lane = threadIdx.x;
    const float* __restrict__ rowbase = in + (size_t)b * TSTEPS * VCLS;

    if (lane < BWID){
        pbA[lane]  = (lane == 0) ? 0.0f : NEGF;
        pnbA[lane] = NEGF;
        lastA[lane] = -1;
        lenA[lane]  = 0;
    }
    __syncthreads();

    for (int t = 0; t < TSTEPS; ++t){
        // ---- 1. log_softmax of row t, XLA-exact: shifted = x - max; lp = shifted - log(seq_sum(exp(shifted))) ----
        const float* row = rowbase + t * VCLS;
        float x0 = row[lane];                                   // lanes 0..63 -> elems 0..63
        float x1 = (lane < 32) ? row[64 + lane] : -INFINITY;    // lanes 0..31 -> elems 64..95
        float m = fmaxf(x0, x1);
        #pragma unroll
        for (int off = 32; off; off >>= 1) m = fmaxf(m, __shfl_xor(m, off));
        float sh0 = __fsub_rn(x0, m);
        float sh1 = 0.0f;
        evS[lane] = exp_xla(sh0);
        if (lane < 32){
            sh1 = __fsub_rn(x1, m);
            evS[64 + lane] = exp_xla(sh1);
        }
        __syncthreads();
        if (lane == 0){
            float s = 0.0f;                                     // strict in-order reduce, init 0
            #pragma unroll
            for (int v = 0; v < VCLS; ++v) s = __fadd_rn(s, evS[v]);
            lsumS = log_xla(s);
        }
        __syncthreads();
        float lsum = lsumS;
        lp[lane] = __fsub_rn(sh0, lsum);
        if (lane < 32) lp[64 + lane] = __fsub_rn(sh1, lsum);
        __syncthreads();

        // ---- 2. per-beam precompute (lanes 0..15) ----
        if (lane < BWID){
            float pb = pbA[lane], pnb = pnbA[lane];
            int lst = lastA[lane];
            float pt = logaddexp_x(pb, pnb);
            ptotA[lane] = pt;
            float npb = pt + lp[CCLS];                          // p_tot + lp_blank
            npbA[lane] = npb;
            float stnb = (lst >= 0) ? (pnb + lp[lst]) : NEGF;
            staynbA[lane] = stnb;
            stayscA[lane] = logaddexp_x(npb, stnb);             // stay candidate score
        }
        __syncthreads();

        // ---- 3. score all 1536 candidates; lane-private key slots k = j*64 + lane ----
        unsigned long long lmax = 0ull;
        #pragma unroll
        for (int j = 0; j < 24; ++j){
            int k = j * 64 + lane;
            float sc;
            if (k < BWID){
                sc = stayscA[k];
            } else {
                int e  = k - BWID;
                int bw = e / CCLS;
                int c  = e - bw * CCLS;
                float bs = (c == lastA[bw]) ? pbA[bw] : ptotA[bw];
                sc = bs + lp[c];
            }
            // key: score-major (ascending ord), tie -> lower candidate idx wins
            unsigned long long key = ((unsigned long long)ford(sc) << 32) | (unsigned)(~(unsigned)k);
            keys[k] = key;
            if (key > lmax) lmax = key;
        }
        // no barrier needed: each lane only ever touches its own key slots

        // ---- 4. top-16 selection: 16 argmax rounds (exact jax.lax.top_k order) ----
        int mysel = 0;
        #pragma unroll 1
        for (int r = 0; r < BWID; ++r){
            unsigned long long wk = lmax;
            #pragma unroll
            for (int off = 32; off; off >>= 1){
                unsigned long long o = __shfl_xor(wk, off);
                if (o > wk) wk = o;
            }
            int widx = (int)(~(unsigned)(wk & 0xFFFFFFFFull));
            if (lane == r) mysel = widx;                        // lane r records round-r winner
            int owner = widx & 63;
            if (lane == owner){                                 // only owner's local max is invalidated
                keys[widx] = 0ull;
                unsigned long long nm = 0ull;
                #pragma unroll
                for (int j = 0; j < 24; ++j){
                    unsigned long long kk = keys[j * 64 + lane];
                    if (kk > nm) nm = kk;
                }
                lmax = nm;
            }
        }

        // ---- 5. beam state update (read old state into regs, barrier, write new) ----
        int nlast = 0, nlen = 0, parent = 0, code = 0;
        float npbV = 0.f, npnbV = 0.f;
        if (lane < BWID){
            int s = mysel;
            if (s < BWID){                                      // stay
                parent = s; code = 0;
                nlast = lastA[s]; nlen = lenA[s];
                npbV = npbA[s]; npnbV = staynbA[s];
            } else {                                            // extend
                int e = s - BWID;
                parent = e / CCLS;
                int c  = e - parent * CCLS;
                code = c + 1;
                nlast = c; nlen = lenA[parent] + 1;
                npbV = NEGF;
                float bs = (c == lastA[parent]) ? pbA[parent] : ptotA[parent];
                npnbV = bs + lp[c];                             // == top score for this candidate
            }
        }
        __syncthreads();
        if (lane < BWID){
            pbA[lane] = npbV; pnbA[lane] = npnbV;
            lastA[lane] = nlast; lenA[lane] = nlen;
            bp[t * BWID + lane] = (unsigned short)((parent << 8) | code);
        }
        __syncthreads();
    }

    // ---- final: pick best beam (tie -> lowest idx), emit outputs ----
    if (lane < BWID) finalsS[lane] = logaddexp_x(pbA[lane], pnbA[lane]);
    __syncthreads();
    if (lane == 0){
        int bi = 0; float bv = finalsS[0];
        for (int i = 1; i < BWID; ++i){
            if (finalsS[i] > bv){ bv = finalsS[i]; bi = i; }
        }
        bestS = bi;
        out[(size_t)NBATCH * TSTEPS + b] = exp_xla(bv);         // probability (underflows to 0.0f)
    }
    __syncthreads();
    int bi = bestS;
    int L  = lenA[bi];
    // pad positions L..T-1 with -1 (disjoint from lane0's char writes below)
    for (int j = L + lane; j < TSTEPS; j += 64) out[(size_t)b * TSTEPS + j] = -1.0f;
    if (lane == 0){
        int beam = bi, pos = L;
        for (int t = TSTEPS - 1; t >= 0; --t){
            unsigned short e = bp[t * BWID + beam];
            int code = e & 0xFF;
            if (code){ out[(size_t)b * TSTEPS + (pos - 1)] = (float)(code - 1); pos--; }
            beam = e >> 8;
        }
    }
}

extern "C" void kernel_launch(void* const* d_in, const int* in_sizes, int n_in,
                              void* d_out, int out_size, void* d_ws, size_t ws_size,
                              hipStream_t stream)
{
    const float* in = (const float*)d_in[0];
    float* out = (float*)d_out;
    hipLaunchKernelGGL(ctc_beam, dim3(NBATCH), dim3(64), 0, stream, in, out);
}

// Round 4
// 6078.496 us; speedup vs baseline: 1.1227x; 1.1227x over previous
//
#include <hip/hip_runtime.h>
#include <math.h>

// CTC prefix beam search, one example per block: 2 waves (consumer=beam step,
// producer=next-row log-softmax). B=512, T=512, V=96 (blank=95), W=16.
// Numerics replicate XLA:CPU f32 op-for-op (verified absmax 0.0 in round 3).
#define NBATCH 512
#define TSTEPS 512
#define VCLS   96
#define CCLS   95
#define BWID   16
#define NEGF   (-1e30f)

// ---------------- XLA:CPU-replica transcendentals (no FMA, explicit rounding) ----------------
__device__ __forceinline__ float exp_xla(float x){
    x = fminf(x, 88.3762626647950f);
    x = fmaxf(x, -88.3762626647949f);
    float t = __fadd_rn(__fmul_rn(x, 1.44269504088896341f), 0.5f);
    float m = floorf(t);
    float r = __fadd_rn(__fmul_rn(m, -0.693359375f), x);
    r = __fadd_rn(__fmul_rn(m, 2.12194440e-4f), r);
    float y = 1.9875691500E-4f;
    y = __fadd_rn(__fmul_rn(y, r), 1.3981999507E-3f);
    y = __fadd_rn(__fmul_rn(y, r), 8.3334519073E-3f);
    y = __fadd_rn(__fmul_rn(y, r), 4.1665795894E-2f);
    y = __fadd_rn(__fmul_rn(y, r), 1.6666665459E-1f);
    y = __fadd_rn(__fmul_rn(y, r), 5.0000001201E-1f);
    float r2 = __fmul_rn(r, r);
    y = __fadd_rn(__fmul_rn(y, r2), r);
    y = __fadd_rn(y, 1.0f);
    int n = (int)m;
    unsigned sb = (unsigned)(n + 127);
    float s = __uint_as_float(sb << 23);
    return __fmul_rn(y, s);
}

__device__ __forceinline__ float log_xla(float x){
    unsigned bits = __float_as_uint(x);
    int e = (int)(bits >> 23) - 126;
    float m = __uint_as_float((bits & 0x007FFFFFu) | 0x3F000000u);
    if (m < 0.707106781186547524f){
        e -= 1;
        m = __fsub_rn(__fadd_rn(m, m), 1.0f);
    } else {
        m = __fsub_rn(m, 1.0f);
    }
    float z = __fmul_rn(m, m);
    float p = 7.0376836292E-2f;
    p = __fadd_rn(__fmul_rn(p, m), -1.1514610310E-1f);
    p = __fadd_rn(__fmul_rn(p, m),  1.1676998740E-1f);
    p = __fadd_rn(__fmul_rn(p, m), -1.2420140846E-1f);
    p = __fadd_rn(__fmul_rn(p, m),  1.4249322787E-1f);
    p = __fadd_rn(__fmul_rn(p, m), -1.6668057665E-1f);
    p = __fadd_rn(__fmul_rn(p, m),  2.0000714765E-1f);
    p = __fadd_rn(__fmul_rn(p, m), -2.4999993993E-1f);
    p = __fadd_rn(__fmul_rn(p, m),  3.3333331174E-1f);
    float y = __fmul_rn(m, __fmul_rn(z, p));
    float fe = (float)e;
    y = __fadd_rn(y, __fmul_rn(-2.12194440e-4f, fe));
    y = __fadd_rn(y, __fmul_rn(-0.5f, z));
    float rr = __fadd_rn(m, y);
    rr = __fadd_rn(rr, __fmul_rn(0.693359375f, fe));
    return rr;
}

__device__ __forceinline__ float log1p_xla(float x){
    float u = __fadd_rn(x, 1.0f);
    if (u == 1.0f) return x;
    float lu = log_xla(u);
    float um1 = __fsub_rn(u, 1.0f);
    return __fmul_rn(lu, __fdiv_rn(x, um1));
}

__device__ __forceinline__ float logaddexp_x(float x, float y){
    float amax = fmaxf(x, y);
    float d = __fsub_rn(x, y);
    float e = exp_xla(-fabsf(d));
    float l1p = log1p_xla(e);
    return __fadd_rn(amax, l1p);
}

// monotone float -> uint (ascending); no NaN/-0 candidates by construction
__device__ __forceinline__ unsigned ford(float f){
    unsigned u = __float_as_uint(f);
    return (u & 0x80000000u) ? ~u : (u | 0x80000000u);
}

// ---------------- intra-wave LDS fence (write->read handoff within one wave) ----------------
__device__ __forceinline__ void wave_fence(){
    asm volatile("s_waitcnt lgkmcnt(0)" ::: "memory");
    __builtin_amdgcn_sched_barrier(0);
}

// ---------------- fast 64-lane u64 max reduce: 4 DPP levels + swizzle + shfl ----------------
template<int CTRL>
__device__ __forceinline__ unsigned long long dpp64(unsigned long long x){
    int lo = (int)(unsigned)x;
    int hi = (int)(unsigned)(x >> 32);
    lo = __builtin_amdgcn_update_dpp(lo, lo, CTRL, 0xF, 0xF, false);
    hi = __builtin_amdgcn_update_dpp(hi, hi, CTRL, 0xF, 0xF, false);
    return ((unsigned long long)(unsigned)hi << 32) | (unsigned)lo;
}
__device__ __forceinline__ unsigned long long swz16_64(unsigned long long x){
    int lo = __builtin_amdgcn_ds_swizzle((int)(unsigned)x, 0x401F);        // lane ^= 16 (BitMode, per ISA doc)
    int hi = __builtin_amdgcn_ds_swizzle((int)(unsigned)(x >> 32), 0x401F);
    return ((unsigned long long)(unsigned)hi << 32) | (unsigned)lo;
}
__device__ __forceinline__ unsigned long long wave_max_u64(unsigned long long v){
    unsigned long long o;
    o = dpp64<0xB1>(v);  if (o > v) v = o;   // quad_perm [1,0,3,2]  : xor1
    o = dpp64<0x4E>(v);  if (o > v) v = o;   // quad_perm [2,3,0,1]  : xor2
    o = dpp64<0x141>(v); if (o > v) v = o;   // row_half_mirror      : cross quads in 8
    o = dpp64<0x140>(v); if (o > v) v = o;   // row_mirror           : cross 8s in 16
    o = swz16_64(v);     if (o > v) v = o;   // ds_swizzle           : xor16 in 32
    o = __shfl_xor(v, 32, 64); if (o > v) v = o;  // cross 32
    return v;
}

// ---------------- producer: bit-exact log-softmax of one row into dst[96] ----------------
__device__ __forceinline__ void produce_lp(const float* __restrict__ row, float* __restrict__ dst,
                                           int lane, float* __restrict__ evS, float* __restrict__ lsumS)
{
    float x0 = row[lane];
    float x1 = (lane < 32) ? row[64 + lane] : -INFINITY;
    float m = fmaxf(x0, x1);
    #pragma unroll
    for (int off = 32; off; off >>= 1) m = fmaxf(m, __shfl_xor(m, off, 64));
    float sh0 = __fsub_rn(x0, m);
    float sh1 = 0.0f;
    evS[lane] = exp_xla(sh0);
    if (lane < 32){
        sh1 = __fsub_rn(x1, m);
        evS[64 + lane] = exp_xla(sh1);
    }
    wave_fence();
    if (lane == 0){
        float s = 0.0f;                               // strict in-order reduce, init 0
        #pragma unroll
        for (int v = 0; v < VCLS; ++v) s = __fadd_rn(s, evS[v]);
        *lsumS = log_xla(s);
    }
    wave_fence();
    float ls = *lsumS;
    dst[lane] = __fsub_rn(sh0, ls);
    if (lane < 32) dst[64 + lane] = __fsub_rn(sh1, ls);
}

__global__ __launch_bounds__(128)
void ctc_beam(const float* __restrict__ in, float* __restrict__ out)
{
    __shared__ float ring[2][VCLS];                 // lp double buffer (producer -> consumer)
    __shared__ float evS[VCLS];                     // producer-private
    __shared__ float lsumS;                         // producer-private
    __shared__ float pbA[BWID], pnbA[BWID], ptotA[BWID], npbA[BWID], staynbA[BWID], stayscA[BWID];
    __shared__ int   lastA[BWID], lenA[BWID];
    __shared__ unsigned short bp[TSTEPS * BWID];    // backpointers: (parent<<8)|(char+1), 0 = stay
    __shared__ float finalsS[BWID];
    __shared__ int bestS;

    const int tid  = threadIdx.x;
    const int wid  = tid >> 6;                      // 0 = consumer, 1 = producer
    const int lane = tid & 63;
    const int b    = blockIdx.x;
    const float* __restrict__ rowbase = in + (size_t)b * TSTEPS * VCLS;

    // ---- prologue ----
    if (wid == 1){
        produce_lp(rowbase, ring[0], lane, evS, &lsumS);
    } else if (lane < BWID){
        pbA[lane]  = (lane == 0) ? 0.0f : NEGF;
        pnbA[lane] = NEGF;
        lastA[lane] = -1;
        lenA[lane]  = 0;
    }
    __syncthreads();

    for (int t = 0; t < TSTEPS; ++t){
        if (wid == 1){
            // producer: lp for step t+1 (fully off the consumer's critical path)
            if (t + 1 < TSTEPS)
                produce_lp(rowbase + (size_t)(t + 1) * VCLS, ring[(t + 1) & 1], lane, evS, &lsumS);
        } else {
            const float* __restrict__ lpc = ring[t & 1];

            // ---- step 2: per-beam precompute (lanes 0..15) ----
            if (lane < BWID){
                float pb = pbA[lane], pnb = pnbA[lane];
                int lst = lastA[lane];
                float pt = logaddexp_x(pb, pnb);
                ptotA[lane] = pt;
                float npb = pt + lpc[CCLS];
                npbA[lane] = npb;
                float stnb = (lst >= 0) ? (pnb + lpc[lst]) : NEGF;
                staynbA[lane] = stnb;
                stayscA[lane] = logaddexp_x(npb, stnb);
            }
            wave_fence();

            // ---- step 3: 24 lane-private keys in REGISTERS (k = j*64 + lane) ----
            unsigned long long kk[24];
            #pragma unroll
            for (int j = 0; j < 24; ++j){
                int k = j * 64 + lane;
                float sc;
                if (j == 0 && lane < BWID){
                    sc = stayscA[lane];
                } else {
                    int e  = k - BWID;
                    int bw = e / CCLS;
                    int c  = e - bw * CCLS;
                    float bs = (c == lastA[bw]) ? pbA[bw] : ptotA[bw];
                    sc = bs + lpc[c];
                }
                kk[j] = ((unsigned long long)ford(sc) << 32) | (unsigned)(~(unsigned)k);
            }
            unsigned long long lmax = kk[0];
            #pragma unroll
            for (int j = 1; j < 24; ++j) lmax = (kk[j] > lmax) ? kk[j] : lmax;

            // ---- step 4: 16 argmax rounds (exact jax.lax.top_k order; keys unique) ----
            int mysel = 0;
            #pragma unroll 1
            for (int r = 0; r < BWID; ++r){
                unsigned long long wk = wave_max_u64(lmax);
                int widx = (int)(~(unsigned)wk);
                if (lane == r) mysel = widx;
                if (r < BWID - 1){
                    unsigned long long nm = 0ull;
                    #pragma unroll
                    for (int j = 0; j < 24; ++j){
                        unsigned long long kj = kk[j];
                        kj = (kj == wk) ? 0ull : kj;     // value-match invalidate (owner only matches)
                        kk[j] = kj;
                        nm = (kj > nm) ? kj : nm;
                    }
                    lmax = nm;
                }
            }

            // ---- step 5: beam state update ----
            int nlast = 0, nlen = 0, parent = 0, code = 0;
            float npbV = 0.f, npnbV = 0.f;
            if (lane < BWID){
                int s = mysel;
                if (s < BWID){                            // stay
                    parent = s; code = 0;
                    nlast = lastA[s]; nlen = lenA[s];
                    npbV = npbA[s]; npnbV = staynbA[s];
                } else {                                  // extend
                    int e = s - BWID;
                    parent = e / CCLS;
                    int c  = e - parent * CCLS;
                    code = c + 1;
                    nlast = c; nlen = lenA[parent] + 1;
                    npbV = NEGF;
                    float bs = (c == lastA[parent]) ? pbA[parent] : ptotA[parent];
                    npnbV = bs + lpc[c];
                }
            }
            wave_fence();
            if (lane < BWID){
                pbA[lane] = npbV; pnbA[lane] = npnbV;
                lastA[lane] = nlast; lenA[lane] = nlen;
                bp[t * BWID + lane] = (unsigned short)((parent << 8) | code);
            }
        }
        __syncthreads();
    }

    // ---- final: consumer wave only (no block barriers below) ----
    if (wid == 0){
        if (lane < BWID) finalsS[lane] = logaddexp_x(pbA[lane], pnbA[lane]);
        wave_fence();
        if (lane == 0){
            int bi = 0; float bv = finalsS[0];
            for (int i = 1; i < BWID; ++i){
                if (finalsS[i] > bv){ bv = finalsS[i]; bi = i; }
            }
            bestS = bi;
            out[(size_t)NBATCH * TSTEPS + b] = exp_xla(bv);   // probability
        }
        wave_fence();
        int bi = bestS;
        int L  = lenA[bi];
        for (int j = L + lane; j < TSTEPS; j += 64) out[(size_t)b * TSTEPS + j] = -1.0f;
        if (lane == 0){
            int beam = bi, pos = L;
            for (int t = TSTEPS - 1; t >= 0; --t){
                unsigned short e = bp[t * BWID + beam];
                int code = e & 0xFF;
                if (code){ out[(size_t)b * TSTEPS + (pos - 1)] = (float)(code - 1); pos--; }
                beam = e >> 8;
            }
        }
    }
}

extern "C" void kernel_launch(void* const* d_in, const int* in_sizes, int n_in,
                              void* d_out, int out_size, void* d_ws, size_t ws_size,
                              hipStream_t stream)
{
    const float* in = (const float*)d_in[0];
    float* out = (float*)d_out;
    hipLaunchKernelGGL(ctc_beam, dim3(NBATCH), dim3(128), 0, stream, in, out);
}

// Round 5
// 4817.994 us; speedup vs baseline: 1.4164x; 1.2616x over previous
//
#include <hip/hip_runtime.h>
#include <math.h>

// CTC prefix beam search, one example per block: 2 waves (consumer=beam step,
// producer=next-row log-softmax). B=512, T=512, V=96 (blank=95), W=16.
// Numerics replicate XLA:CPU f32 op-for-op (verified absmax 0.0 in rounds 3/4).
// R5: all-DPP reduces (no LDS in dependent chains), candidate remap for
// structured LDS access, register-mirrored beam state, tree reductions.
#define NBATCH 512
#define TSTEPS 512
#define VCLS   96
#define CCLS   95
#define BWID   16
#define NEGF   (-1e30f)

typedef unsigned long long u64;
typedef unsigned int u32;

// ---------------- XLA:CPU-replica transcendentals (no FMA, explicit rounding) ----------------
__device__ __forceinline__ float exp_xla(float x){
    x = fminf(x, 88.3762626647950f);
    x = fmaxf(x, -88.3762626647949f);
    float t = __fadd_rn(__fmul_rn(x, 1.44269504088896341f), 0.5f);
    float m = floorf(t);
    float r = __fadd_rn(__fmul_rn(m, -0.693359375f), x);
    r = __fadd_rn(__fmul_rn(m, 2.12194440e-4f), r);
    float y = 1.9875691500E-4f;
    y = __fadd_rn(__fmul_rn(y, r), 1.3981999507E-3f);
    y = __fadd_rn(__fmul_rn(y, r), 8.3334519073E-3f);
    y = __fadd_rn(__fmul_rn(y, r), 4.1665795894E-2f);
    y = __fadd_rn(__fmul_rn(y, r), 1.6666665459E-1f);
    y = __fadd_rn(__fmul_rn(y, r), 5.0000001201E-1f);
    float r2 = __fmul_rn(r, r);
    y = __fadd_rn(__fmul_rn(y, r2), r);
    y = __fadd_rn(y, 1.0f);
    int n = (int)m;
    unsigned sb = (unsigned)(n + 127);
    float s = __uint_as_float(sb << 23);
    return __fmul_rn(y, s);
}

__device__ __forceinline__ float log_xla(float x){
    unsigned bits = __float_as_uint(x);
    int e = (int)(bits >> 23) - 126;
    float m = __uint_as_float((bits & 0x007FFFFFu) | 0x3F000000u);
    if (m < 0.707106781186547524f){
        e -= 1;
        m = __fsub_rn(__fadd_rn(m, m), 1.0f);
    } else {
        m = __fsub_rn(m, 1.0f);
    }
    float z = __fmul_rn(m, m);
    float p = 7.0376836292E-2f;
    p = __fadd_rn(__fmul_rn(p, m), -1.1514610310E-1f);
    p = __fadd_rn(__fmul_rn(p, m),  1.1676998740E-1f);
    p = __fadd_rn(__fmul_rn(p, m), -1.2420140846E-1f);
    p = __fadd_rn(__fmul_rn(p, m),  1.4249322787E-1f);
    p = __fadd_rn(__fmul_rn(p, m), -1.6668057665E-1f);
    p = __fadd_rn(__fmul_rn(p, m),  2.0000714765E-1f);
    p = __fadd_rn(__fmul_rn(p, m), -2.4999993993E-1f);
    p = __fadd_rn(__fmul_rn(p, m),  3.3333331174E-1f);
    float y = __fmul_rn(m, __fmul_rn(z, p));
    float fe = (float)e;
    y = __fadd_rn(y, __fmul_rn(-2.12194440e-4f, fe));
    y = __fadd_rn(y, __fmul_rn(-0.5f, z));
    float rr = __fadd_rn(m, y);
    rr = __fadd_rn(rr, __fmul_rn(0.693359375f, fe));
    return rr;
}

__device__ __forceinline__ float log1p_xla(float x){
    float u = __fadd_rn(x, 1.0f);
    if (u == 1.0f) return x;
    float lu = log_xla(u);
    float um1 = __fsub_rn(u, 1.0f);
    return __fmul_rn(lu, __fdiv_rn(x, um1));
}

__device__ __forceinline__ float logaddexp_x(float x, float y){
    float amax = fmaxf(x, y);
    float d = __fsub_rn(x, y);
    float e = exp_xla(-fabsf(d));
    float l1p = log1p_xla(e);
    return __fadd_rn(amax, l1p);
}

// monotone float -> uint (ascending); no NaN/-0 candidates by construction
__device__ __forceinline__ unsigned ford(float f){
    unsigned u = __float_as_uint(f);
    return (u & 0x80000000u) ? ~u : (u | 0x80000000u);
}

// ---------------- intra-wave LDS fence ----------------
__device__ __forceinline__ void wave_fence(){
    asm volatile("s_waitcnt lgkmcnt(0)" ::: "memory");
    __builtin_amdgcn_sched_barrier(0);
}

// ---------------- all-DPP wave reduces (no LDS ops) ----------------
// levels: xor1, xor2, half_mirror(8), mirror(16), bcast15, bcast31 -> lane63 has max
template<int CTRL>
__device__ __forceinline__ u64 dmax64(u64 v){
    int lo = __builtin_amdgcn_update_dpp((int)(u32)v, (int)(u32)v, CTRL, 0xF, 0xF, false);
    int hi = __builtin_amdgcn_update_dpp((int)(u32)(v >> 32), (int)(u32)(v >> 32), CTRL, 0xF, 0xF, false);
    u64 o = ((u64)(u32)hi << 32) | (u32)lo;
    return (o > v) ? o : v;
}
__device__ __forceinline__ u64 wave_max64(u64 v){
    v = dmax64<0xB1>(v);      // quad_perm [1,0,3,2]
    v = dmax64<0x4E>(v);      // quad_perm [2,3,0,1]
    v = dmax64<0x141>(v);     // row_half_mirror
    v = dmax64<0x140>(v);     // row_mirror
    v = dmax64<0x142>(v);     // row_bcast15
    v = dmax64<0x143>(v);     // row_bcast31
    u32 lo = (u32)__builtin_amdgcn_readlane((int)(u32)v, 63);
    u32 hi = (u32)__builtin_amdgcn_readlane((int)(u32)(v >> 32), 63);
    return ((u64)hi << 32) | lo;
}
template<int CTRL>
__device__ __forceinline__ float dmaxf(float v){
    int o = __builtin_amdgcn_update_dpp(__float_as_int(v), __float_as_int(v), CTRL, 0xF, 0xF, false);
    return fmaxf(v, __int_as_float(o));
}
__device__ __forceinline__ float wave_maxf(float v){
    v = dmaxf<0xB1>(v); v = dmaxf<0x4E>(v); v = dmaxf<0x141>(v);
    v = dmaxf<0x140>(v); v = dmaxf<0x142>(v); v = dmaxf<0x143>(v);
    return __int_as_float(__builtin_amdgcn_readlane(__float_as_int(v), 63));
}

#define UM(a,b) (((a) > (b)) ? (a) : (b))
__device__ __forceinline__ u64 tree_max24(const u64* kk){
    u64 t0=UM(kk[0],kk[1]),  t1=UM(kk[2],kk[3]),  t2=UM(kk[4],kk[5]),  t3=UM(kk[6],kk[7]);
    u64 t4=UM(kk[8],kk[9]),  t5=UM(kk[10],kk[11]),t6=UM(kk[12],kk[13]),t7=UM(kk[14],kk[15]);
    u64 t8=UM(kk[16],kk[17]),t9=UM(kk[18],kk[19]),t10=UM(kk[20],kk[21]),t11=UM(kk[22],kk[23]);
    u64 u0=UM(t0,t1), u1=UM(t2,t3), u2=UM(t4,t5), u3=UM(t6,t7), u4=UM(t8,t9), u5=UM(t10,t11);
    u64 v0=UM(u0,u1), v1=UM(u2,u3), v2=UM(u4,u5);
    return UM(UM(v0,v1), v2);
}

// ---------------- producer: bit-exact log-softmax of one row into dst[96] ----------------
__device__ __forceinline__ void produce_lp(const float* __restrict__ row, float* __restrict__ dst,
                                           int lane, float* __restrict__ evS)
{
    float x0 = row[lane];
    float x1 = (lane < 32) ? row[64 + lane] : -INFINITY;
    float m = wave_maxf(fmaxf(x0, x1));       // exact max, order-independent
    float sh0 = __fsub_rn(x0, m);
    float sh1 = 0.0f;
    evS[lane] = exp_xla(sh0);
    if (lane < 32){
        sh1 = __fsub_rn(x1, m);
        evS[64 + lane] = exp_xla(sh1);
    }
    wave_fence();
    float ls = 0.0f;
    if (lane == 0){
        float s = 0.0f;                        // strict in-order reduce, init 0
        const float4* e4 = (const float4*)evS;
        #pragma unroll
        for (int g = 0; g < 24; ++g){
            float4 w = e4[g];
            s = __fadd_rn(s, w.x); s = __fadd_rn(s, w.y);
            s = __fadd_rn(s, w.z); s = __fadd_rn(s, w.w);
        }
        ls = log_xla(s);
    }
    ls = __int_as_float(__builtin_amdgcn_readlane(__float_as_int(ls), 0));
    dst[lane] = __fsub_rn(sh0, ls);
    if (lane < 32) dst[64 + lane] = __fsub_rn(sh1, ls);
}

__global__ __launch_bounds__(128)
void ctc_beam(const float* __restrict__ in, float* __restrict__ out)
{
    __shared__ __align__(16) float ring[2][VCLS];   // lp double buffer (producer -> consumer)
    __shared__ __align__(16) float evS[VCLS];       // producer-private
    __shared__ float pbS[BWID], ptotS[BWID], npbS[BWID], staynbS[BWID], stayscS[BWID];
    __shared__ int   lastS[BWID], lenS[BWID];
    __shared__ unsigned short bp[TSTEPS * BWID];    // backpointers: (parent<<8)|(char+1), 0 = stay
    __shared__ float finalsS[BWID];

    const int tid  = threadIdx.x;
    const int wid  = tid >> 6;                      // 0 = consumer, 1 = producer
    const int lane = tid & 63;
    const int b    = blockIdx.x;
    const float* __restrict__ rowbase = in + (size_t)b * TSTEPS * VCLS;

    // consumer beam-state register mirror (lanes 0..15 of wave 0)
    float pb_r = NEGF, pnb_r = NEGF;
    int last_r = -1, len_r = 0;

    // candidate remap: lane covers beam b4 = lane>>2, chars c = q*24 + i (i<24);
    // slot (q==3, i==23) (c==95, invalid) carries the STAY candidate of beam b4.
    const int q  = lane & 3;
    const int b4 = lane >> 2;
    const int q24 = q * 24;
    const int kbase = BWID + b4 * CCLS + q24;       // ext candidate idx for slot i: kbase + i

    // ---- prologue ----
    if (wid == 1){
        produce_lp(rowbase, ring[0], lane, evS);
    } else if (lane < BWID){
        pb_r = (lane == 0) ? 0.0f : NEGF;
        pnb_r = NEGF; last_r = -1; len_r = 0;
        pbS[lane] = pb_r; lastS[lane] = -1; lenS[lane] = 0;
    }
    __syncthreads();

    for (int t = 0; t < TSTEPS; ++t){
        if (wid == 1){
            if (t + 1 < TSTEPS)
                produce_lp(rowbase + (size_t)(t + 1) * VCLS, ring[(t + 1) & 1], lane, evS);
        } else {
            const float* __restrict__ lpc = ring[t & 1];

            // ---- early structured loads: this lane's 24 consecutive lp values ----
            float la[24];
            {
                const float4* lp4 = (const float4*)lpc + q * 6;
                #pragma unroll
                for (int g = 0; g < 6; ++g){
                    float4 w = lp4[g];
                    la[g*4+0] = w.x; la[g*4+1] = w.y; la[g*4+2] = w.z; la[g*4+3] = w.w;
                }
            }

            // ---- step 2: per-beam precompute on register state (lanes 0..15) ----
            if (lane < BWID){
                float lpb = lpc[CCLS];
                float lpl = lpc[(last_r >= 0) ? last_r : 0];
                float pt  = logaddexp_x(pb_r, pnb_r);
                float npb = pt + lpb;
                float stnb = (last_r >= 0) ? (pnb_r + lpl) : NEGF;
                float stay = logaddexp_x(npb, stnb);
                ptotS[lane] = pt; npbS[lane] = npb;
                staynbS[lane] = stnb; stayscS[lane] = stay;
            }
            wave_fence();

            // ---- broadcast-style beam state reads (4 lanes share each address) ----
            float pb_b   = pbS[b4];
            float pt_b   = ptotS[b4];
            int   last_b = lastS[b4];
            float stay_b = stayscS[b4];

            // ---- step 3: build 24 keys in registers + tree max ----
            u64 kk[24];
            #pragma unroll
            for (int i = 0; i < 24; ++i){
                int c = q24 + i;
                float sc = ((c == last_b) ? pb_b : pt_b) + la[i];
                int k = kbase + i;
                if (q == 3 && i == 23){ sc = stay_b; k = b4; }   // stay slot
                kk[i] = ((u64)ford(sc) << 32) | (u32)(~(u32)k);
            }
            u64 lmax = tree_max24(kk);

            // ---- step 4: 16 argmax rounds, all-DPP (exact jax.lax.top_k order) ----
            int mysel = 0;
            #pragma unroll 1
            for (int r = 0; r < BWID; ++r){
                u64 wk = wave_max64(lmax);            // uniform (SGPR) global max
                if (lane == r) mysel = (int)(~(u32)wk);
                if (r < BWID - 1){
                    #pragma unroll
                    for (int j = 0; j < 24; ++j)
                        kk[j] = (kk[j] == wk) ? 0ull : kk[j];   // keys unique -> only owner matches
                    lmax = tree_max24(kk);
                }
            }

            // ---- step 5: beam state update ----
            int nlast = 0, nlen = 0, parent = 0, code = 0;
            float npbV = 0.f, npnbV = 0.f;
            if (lane < BWID){
                int s = mysel;
                if (s < BWID){                         // stay
                    parent = s; code = 0;
                    nlast = lastS[s]; nlen = lenS[s];
                    npbV = npbS[s]; npnbV = staynbS[s];
                } else {                               // extend
                    u32 e = (u32)(s - BWID);
                    parent = (int)((e * 44151u) >> 22);        // exact e/95 for e<1520
                    int c = (int)(e - (u32)parent * 95u);
                    code = c + 1;
                    nlast = c; nlen = lenS[parent] + 1;
                    npbV = NEGF;
                    float bs = (c == lastS[parent]) ? pbS[parent] : ptotS[parent];
                    npnbV = bs + lpc[c];
                }
            }
            wave_fence();
            if (lane < BWID){
                pbS[lane] = npbV; lastS[lane] = nlast; lenS[lane] = nlen;
                pb_r = npbV; pnb_r = npnbV; last_r = nlast; len_r = nlen;
                bp[t * BWID + lane] = (unsigned short)((parent << 8) | code);
            }
        }
        __syncthreads();
    }

    // ---- final: consumer wave only ----
    if (wid == 0){
        if (lane < BWID) finalsS[lane] = logaddexp_x(pb_r, pnb_r);
        wave_fence();
        int bi_loc = 0;
        if (lane == 0){
            float bv = finalsS[0];
            for (int i = 1; i < BWID; ++i){
                if (finalsS[i] > bv){ bv = finalsS[i]; bi_loc = i; }
            }
            out[(size_t)NBATCH * TSTEPS + b] = exp_xla(bv);   // probability
        }
        int bi = __builtin_amdgcn_readlane(bi_loc, 0);
        int L  = lenS[bi];
        for (int j = L + lane; j < TSTEPS; j += 64) out[(size_t)b * TSTEPS + j] = -1.0f;
        if (lane == 0){
            int beam = bi, pos = L;
            for (int t = TSTEPS - 1; t >= 0; --t){
                unsigned short e = bp[t * BWID + beam];
                int code = e & 0xFF;
                if (code){ out[(size_t)b * TSTEPS + (pos - 1)] = (float)(code - 1); pos--; }
                beam = e >> 8;
            }
        }
    }
}

extern "C" void kernel_launch(void* const* d_in, const int* in_sizes, int n_in,
                              void* d_out, int out_size, void* d_ws, size_t ws_size,
                              hipStream_t stream)
{
    const float* in = (const float*)d_in[0];
    float* out = (float*)d_out;
    hipLaunchKernelGGL(ctc_beam, dim3(NBATCH), dim3(128), 0, stream, in, out);
}

// Round 7
// 3084.072 us; speedup vs baseline: 2.2128x; 1.5622x over previous
//
#include <hip/hip_runtime.h>
#include <math.h>

// CTC prefix beam search, one example per block: 2 waves (consumer=beam step,
// producer=next-row log-softmax). B=512, T=512, V=96 (blank=95), W=16.
// Numerics replicate XLA:CPU f32 op-for-op (verified absmax 0.0 in r3/r4/r5).
// R6: f64-packed keys (v_max_f64 single-inst max; u64-order == f64-order by
// construction), quad-mirrored beam state (no LDS fence before key build),
// all-lane winner decode (one cndmask per round).
#define NBATCH 512
#define TSTEPS 512
#define VCLS   96
#define CCLS   95
#define BWID   16
#define NEGF   (-1e30f)

typedef unsigned long long u64;
typedef unsigned int u32;

// ---------------- XLA:CPU-replica transcendentals (no FMA, explicit rounding) ----------------
__device__ __forceinline__ float exp_xla(float x){
    x = fminf(x, 88.3762626647950f);
    x = fmaxf(x, -88.3762626647949f);
    float t = __fadd_rn(__fmul_rn(x, 1.44269504088896341f), 0.5f);
    float m = floorf(t);
    float r = __fadd_rn(__fmul_rn(m, -0.693359375f), x);
    r = __fadd_rn(__fmul_rn(m, 2.12194440e-4f), r);
    float y = 1.9875691500E-4f;
    y = __fadd_rn(__fmul_rn(y, r), 1.3981999507E-3f);
    y = __fadd_rn(__fmul_rn(y, r), 8.3334519073E-3f);
    y = __fadd_rn(__fmul_rn(y, r), 4.1665795894E-2f);
    y = __fadd_rn(__fmul_rn(y, r), 1.6666665459E-1f);
    y = __fadd_rn(__fmul_rn(y, r), 5.0000001201E-1f);
    float r2 = __fmul_rn(r, r);
    y = __fadd_rn(__fmul_rn(y, r2), r);
    y = __fadd_rn(y, 1.0f);
    int n = (int)m;
    unsigned sb = (unsigned)(n + 127);
    float s = __uint_as_float(sb << 23);
    return __fmul_rn(y, s);
}

__device__ __forceinline__ float log_xla(float x){
    unsigned bits = __float_as_uint(x);
    int e = (int)(bits >> 23) - 126;
    float m = __uint_as_float((bits & 0x007FFFFFu) | 0x3F000000u);
    if (m < 0.707106781186547524f){
        e -= 1;
        m = __fsub_rn(__fadd_rn(m, m), 1.0f);
    } else {
        m = __fsub_rn(m, 1.0f);
    }
    float z = __fmul_rn(m, m);
    float p = 7.0376836292E-2f;
    p = __fadd_rn(__fmul_rn(p, m), -1.1514610310E-1f);
    p = __fadd_rn(__fmul_rn(p, m),  1.1676998740E-1f);
    p = __fadd_rn(__fmul_rn(p, m), -1.2420140846E-1f);
    p = __fadd_rn(__fmul_rn(p, m),  1.4249322787E-1f);
    p = __fadd_rn(__fmul_rn(p, m), -1.6668057665E-1f);
    p = __fadd_rn(__fmul_rn(p, m),  2.0000714765E-1f);
    p = __fadd_rn(__fmul_rn(p, m), -2.4999993993E-1f);
    p = __fadd_rn(__fmul_rn(p, m),  3.3333331174E-1f);
    float y = __fmul_rn(m, __fmul_rn(z, p));
    float fe = (float)e;
    y = __fadd_rn(y, __fmul_rn(-2.12194440e-4f, fe));
    y = __fadd_rn(y, __fmul_rn(-0.5f, z));
    float rr = __fadd_rn(m, y);
    rr = __fadd_rn(rr, __fmul_rn(0.693359375f, fe));
    return rr;
}

__device__ __forceinline__ float log1p_xla(float x){
    float u = __fadd_rn(x, 1.0f);
    if (u == 1.0f) return x;
    float lu = log_xla(u);
    float um1 = __fsub_rn(u, 1.0f);
    return __fmul_rn(lu, __fdiv_rn(x, um1));
}

__device__ __forceinline__ float logaddexp_x(float x, float y){
    float amax = fmaxf(x, y);
    float d = __fsub_rn(x, y);
    float e = exp_xla(-fabsf(d));
    float l1p = log1p_xla(e);
    return __fadd_rn(amax, l1p);
}

// monotone float -> uint (ascending); no NaN/-0 candidates by construction
__device__ __forceinline__ unsigned ford(float f){
    unsigned u = __float_as_uint(f);
    return (u & 0x80000000u) ? ~u : (u | 0x80000000u);
}

// ---------------- f64-packed selection keys ----------------
// k_u64 = (ford << 31) | (idxinv << 20); bit63 = 0, exponent field in (0,0x7FF)
// for all reachable scores -> positive normal f64; f64 order == u64 order ==
// (score, ~idx) lexicographic. v_max_f64 = one-instruction 64-bit max.
__device__ __forceinline__ double packkey(float sc, int k){
    u64 kb = ((u64)ford(sc) << 31) | ((u64)((~(u32)k) & 0x7FFu) << 20);
    return __longlong_as_double((long long)kb);
}
__device__ __forceinline__ int decodekey(double wk){
    u32 idxinv = (u32)((u64)__double_as_longlong(wk) >> 20) & 0x7FFu;
    return (int)((~idxinv) & 0x7FFu);
}

// ---------------- intra-wave LDS fence ----------------
__device__ __forceinline__ void wave_fence(){
    asm volatile("s_waitcnt lgkmcnt(0)" ::: "memory");
    __builtin_amdgcn_sched_barrier(0);
}

// ---------------- all-DPP wave reduces ----------------
template<int CTRL>
__device__ __forceinline__ double dmaxd(double v){
    long long x = __double_as_longlong(v);
    int lo = __builtin_amdgcn_update_dpp((int)(u32)x, (int)(u32)x, CTRL, 0xF, 0xF, false);
    int hi = __builtin_amdgcn_update_dpp((int)(u32)(x >> 32), (int)(u32)(x >> 32), CTRL, 0xF, 0xF, false);
    double o = __longlong_as_double((long long)(((u64)(u32)hi << 32) | (u32)lo));
    return fmax(v, o);
}
__device__ __forceinline__ double wave_maxd(double v){
    v = dmaxd<0xB1>(v);      // quad_perm [1,0,3,2]
    v = dmaxd<0x4E>(v);      // quad_perm [2,3,0,1]
    v = dmaxd<0x141>(v);     // row_half_mirror
    v = dmaxd<0x140>(v);     // row_mirror
    v = dmaxd<0x142>(v);     // row_bcast15
    v = dmaxd<0x143>(v);     // row_bcast31
    long long x = __double_as_longlong(v);
    u32 lo = (u32)__builtin_amdgcn_readlane((int)(u32)x, 63);
    u32 hi = (u32)__builtin_amdgcn_readlane((int)(u32)(x >> 32), 63);
    return __longlong_as_double((long long)(((u64)hi << 32) | lo));
}
template<int CTRL>
__device__ __forceinline__ float dmaxf(float v){
    int o = __builtin_amdgcn_update_dpp(__float_as_int(v), __float_as_int(v), CTRL, 0xF, 0xF, false);
    return fmaxf(v, __int_as_float(o));
}
__device__ __forceinline__ float wave_maxf(float v){
    v = dmaxf<0xB1>(v); v = dmaxf<0x4E>(v); v = dmaxf<0x141>(v);
    v = dmaxf<0x140>(v); v = dmaxf<0x142>(v); v = dmaxf<0x143>(v);
    return __int_as_float(__builtin_amdgcn_readlane(__float_as_int(v), 63));
}

__device__ __forceinline__ double tree_max24(const double* kk){
    double t0=fmax(kk[0],kk[1]),  t1=fmax(kk[2],kk[3]),  t2=fmax(kk[4],kk[5]),  t3=fmax(kk[6],kk[7]);
    double t4=fmax(kk[8],kk[9]),  t5=fmax(kk[10],kk[11]),t6=fmax(kk[12],kk[13]),t7=fmax(kk[14],kk[15]);
    double t8=fmax(kk[16],kk[17]),t9=fmax(kk[18],kk[19]),t10=fmax(kk[20],kk[21]),t11=fmax(kk[22],kk[23]);
    double u0=fmax(t0,t1), u1=fmax(t2,t3), u2=fmax(t4,t5), u3=fmax(t6,t7), u4=fmax(t8,t9), u5=fmax(t10,t11);
    double v0=fmax(u0,u1), v1=fmax(u2,u3), v2=fmax(u4,u5);
    return fmax(fmax(v0,v1), v2);
}

// ---------------- producer: bit-exact log-softmax of one row into dst[96] ----------------
__device__ __forceinline__ void produce_lp(const float* __restrict__ row, float* __restrict__ dst,
                                           int lane, float* __restrict__ evS)
{
    float x0 = row[lane];
    float x1 = (lane < 32) ? row[64 + lane] : -INFINITY;
    float m = wave_maxf(fmaxf(x0, x1));       // exact max, order-independent
    float sh0 = __fsub_rn(x0, m);
    float sh1 = 0.0f;
    evS[lane] = exp_xla(sh0);
    if (lane < 32){
        sh1 = __fsub_rn(x1, m);
        evS[64 + lane] = exp_xla(sh1);
    }
    wave_fence();
    float ls = 0.0f;
    if (lane == 0){
        float s = 0.0f;                        // strict in-order reduce, init 0
        const float4* e4 = (const float4*)evS;
        #pragma unroll
        for (int g = 0; g < 24; ++g){
            float4 w = e4[g];
            s = __fadd_rn(s, w.x); s = __fadd_rn(s, w.y);
            s = __fadd_rn(s, w.z); s = __fadd_rn(s, w.w);
        }
        ls = log_xla(s);
    }
    ls = __int_as_float(__builtin_amdgcn_readlane(__float_as_int(ls), 0));
    dst[lane] = __fsub_rn(sh0, ls);
    if (lane < 32) dst[64 + lane] = __fsub_rn(sh1, ls);
}

__global__ __launch_bounds__(128)
void ctc_beam(const float* __restrict__ in, float* __restrict__ out)
{
    __shared__ __align__(16) float ring[2][VCLS];   // lp double buffer (producer -> consumer)
    __shared__ __align__(16) float evS[VCLS];       // producer-private
    __shared__ float pbS[BWID], ptotS[BWID], npbS[BWID], staynbS[BWID];
    __shared__ int   lastS[BWID], lenS[BWID];
    __shared__ unsigned short bp[TSTEPS * BWID];    // backpointers: (parent<<8)|(char+1), 0 = stay
    __shared__ float finalsS[BWID];

    const int tid  = threadIdx.x;
    const int wid  = tid >> 6;                      // 0 = consumer, 1 = producer
    const int lane = tid & 63;
    const int b    = blockIdx.x;
    const float* __restrict__ rowbase = in + (size_t)b * TSTEPS * VCLS;

    // quad-mirrored beam state: every lane holds the state of beam b4 = lane>>2
    const int q  = lane & 3;
    const int b4 = lane >> 2;
    const int q24 = q * 24;
    const int kbase = BWID + b4 * CCLS + q24;       // ext candidate idx for slot i: kbase + i

    float pb_r = NEGF, pnb_r = NEGF;
    int last_r = -1, len_r = 0;

    // ---- prologue ----
    if (wid == 1){
        produce_lp(rowbase, ring[0], lane, evS);
    } else {
        pb_r = (b4 == 0) ? 0.0f : NEGF;
        pnb_r = NEGF; last_r = -1; len_r = 0;
        if (q == 0){
            pbS[b4] = pb_r; lastS[b4] = -1; lenS[b4] = 0;
        }
    }
    __syncthreads();

    for (int t = 0; t < TSTEPS; ++t){
        if (wid == 1){
            if (t + 1 < TSTEPS)
                produce_lp(rowbase + (size_t)(t + 1) * VCLS, ring[(t + 1) & 1], lane, evS);
        } else {
            const float* __restrict__ lpc = ring[t & 1];

            // ---- early structured loads: this lane's 24 consecutive lp values ----
            float la[24];
            {
                const float4* lp4 = (const float4*)lpc + q * 6;
                #pragma unroll
                for (int g = 0; g < 6; ++g){
                    float4 w = lp4[g];
                    la[g*4+0] = w.x; la[g*4+1] = w.y; la[g*4+2] = w.z; la[g*4+3] = w.w;
                }
            }

            // ---- step 2: per-beam precompute, redundantly in all 4 lanes of each quad ----
            float lpb = lpc[CCLS];
            float lpl = lpc[(last_r >= 0) ? last_r : 0];
            float pt  = logaddexp_x(pb_r, pnb_r);
            float npb = pt + lpb;
            float stnb = (last_r >= 0) ? (pnb_r + lpl) : NEGF;
            float stay = logaddexp_x(npb, stnb);
            if (q == 0){                       // cross-beam copies for step 5 (fenced later)
                ptotS[b4] = pt; npbS[b4] = npb; staynbS[b4] = stnb;
            }

            // ---- step 3: build 24 keys in registers (no LDS handoff) + tree max ----
            double kk[24];
            #pragma unroll
            for (int i = 0; i < 24; ++i){
                int c = q24 + i;
                float sc = ((c == last_r) ? pb_r : pt) + la[i];
                int k = kbase + i;
                if (q == 3 && i == 23){ sc = stay; k = b4; }   // stay slot (c==95 invalid)
                kk[i] = packkey(sc, k);
            }
            double lmax = tree_max24(kk);

            // ---- step 4: 16 argmax rounds, v_max_f64 (exact jax.lax.top_k order) ----
            int mysel = 0;
            #pragma unroll 1
            for (int r = 0; r < BWID; ++r){
                double wk = wave_maxd(lmax);           // wave-uniform global max
                int widx = decodekey(wk);
                if (b4 == r) mysel = widx;             // each quad records its beam's winner
                if (r < BWID - 1){
                    long long wkb = __double_as_longlong(wk);
                    #pragma unroll
                    for (int j = 0; j < 24; ++j)
                        kk[j] = (__double_as_longlong(kk[j]) == wkb) ? 0.0 : kk[j];
                    lmax = tree_max24(kk);
                }
            }

            // ---- step 5: per-lane new state for own beam; q==0 writes shared ----
            wave_fence();                              // step-2 LDS writes -> step-5 reads
            int nlast, nlen, parent, code;
            float npbV, npnbV;
            {
                int s = mysel;
                if (s < BWID){                         // stay
                    parent = s; code = 0;
                    nlast = lastS[s]; nlen = lenS[s];
                    npbV = npbS[s]; npnbV = staynbS[s];
                } else {                               // extend
                    u32 e = (u32)(s - BWID);
                    parent = (int)((e * 44151u) >> 22);        // exact e/95 for e<1520
                    int c = (int)(e - (u32)parent * 95u);
                    code = c + 1;
                    nlast = c; nlen = lenS[parent] + 1;
                    npbV = NEGF;
                    float bs = (c == lastS[parent]) ? pbS[parent] : ptotS[parent];
                    npnbV = bs + lpc[c];
                }
            }
            wave_fence();                              // all reads done before writes
            pb_r = npbV; pnb_r = npnbV; last_r = nlast; len_r = nlen;
            if (q == 0){
                pbS[b4] = npbV; lastS[b4] = nlast; lenS[b4] = nlen;
                bp[t * BWID + b4] = (unsigned short)((parent << 8) | code);
            }
        }
        __syncthreads();
    }

    // ---- final: consumer wave only ----
    if (wid == 0){
        if (q == 0) finalsS[b4] = logaddexp_x(pb_r, pnb_r);
        wave_fence();
        int bi_loc = 0;
        if (lane == 0){
            float bv = finalsS[0];
            for (int i = 1; i < BWID; ++i){
                if (finalsS[i] > bv){ bv = finalsS[i]; bi_loc = i; }
            }
            out[(size_t)NBATCH * TSTEPS + b] = exp_xla(bv);   // probability
        }
        int bi = __builtin_amdgcn_readlane(bi_loc, 0);
        int L  = lenS[bi];
        for (int j = L + lane; j < TSTEPS; j += 64) out[(size_t)b * TSTEPS + j] = -1.0f;
        if (lane == 0){
            int beam = bi, pos = L;
            for (int t = TSTEPS - 1; t >= 0; --t){
                unsigned short e = bp[t * BWID + beam];
                int code = e & 0xFF;
                if (code){ out[(size_t)b * TSTEPS + (pos - 1)] = (float)(code - 1); pos--; }
                beam = e >> 8;
            }
        }
    }
}

extern "C" void kernel_launch(void* const* d_in, const int* in_sizes, int n_in,
                              void* d_out, int out_size, void* d_ws, size_t ws_size,
                              hipStream_t stream)
{
    const float* in = (const float*)d_in[0];
    float* out = (float*)d_out;
    hipLaunchKernelGGL(ctc_beam, dim3(NBATCH), dim3(128), 0, stream, in, out);
}

// Round 9
// 2907.126 us; speedup vs baseline: 2.3475x; 1.0609x over previous
//
#include <hip/hip_runtime.h>
#include <math.h>

// CTC prefix beam search, one example per block: 2 waves (consumer=beam step,
// producer=next-row log-softmax + lp top-17 sort). B=512, T=512, V=96, W=16.
// Numerics replicate XLA:CPU f32 op-for-op (verified absmax 0.0 r3/r4/r5/r7).
// R9 = R8 merge-stream selection + TIE REPAIR: adding pt to sorted lp can
// produce bit-equal sums (ulp(pt)~1e-4 late), where top_k order is by index,
// not lp order. All inversions sit inside equal-score runs -> two bubble
// passes over st[] restore exact (score,~idx) key order (runs<=3 w.h.p.).
#define NBATCH 512
#define TSTEPS 512
#define VCLS   96
#define CCLS   95
#define BWID   16
#define NEGF   (-1e30f)

typedef unsigned long long u64;
typedef unsigned int u32;

// ---------------- XLA:CPU-replica transcendentals (no FMA, explicit rounding) ----------------
__device__ __forceinline__ float exp_xla(float x){
    x = fminf(x, 88.3762626647950f);
    x = fmaxf(x, -88.3762626647949f);
    float t = __fadd_rn(__fmul_rn(x, 1.44269504088896341f), 0.5f);
    float m = floorf(t);
    float r = __fadd_rn(__fmul_rn(m, -0.693359375f), x);
    r = __fadd_rn(__fmul_rn(m, 2.12194440e-4f), r);
    float y = 1.9875691500E-4f;
    y = __fadd_rn(__fmul_rn(y, r), 1.3981999507E-3f);
    y = __fadd_rn(__fmul_rn(y, r), 8.3334519073E-3f);
    y = __fadd_rn(__fmul_rn(y, r), 4.1665795894E-2f);
    y = __fadd_rn(__fmul_rn(y, r), 1.6666665459E-1f);
    y = __fadd_rn(__fmul_rn(y, r), 5.0000001201E-1f);
    float r2 = __fmul_rn(r, r);
    y = __fadd_rn(__fmul_rn(y, r2), r);
    y = __fadd_rn(y, 1.0f);
    int n = (int)m;
    unsigned sb = (unsigned)(n + 127);
    float s = __uint_as_float(sb << 23);
    return __fmul_rn(y, s);
}

__device__ __forceinline__ float log_xla(float x){
    unsigned bits = __float_as_uint(x);
    int e = (int)(bits >> 23) - 126;
    float m = __uint_as_float((bits & 0x007FFFFFu) | 0x3F000000u);
    if (m < 0.707106781186547524f){
        e -= 1;
        m = __fsub_rn(__fadd_rn(m, m), 1.0f);
    } else {
        m = __fsub_rn(m, 1.0f);
    }
    float z = __fmul_rn(m, m);
    float p = 7.0376836292E-2f;
    p = __fadd_rn(__fmul_rn(p, m), -1.1514610310E-1f);
    p = __fadd_rn(__fmul_rn(p, m),  1.1676998740E-1f);
    p = __fadd_rn(__fmul_rn(p, m), -1.2420140846E-1f);
    p = __fadd_rn(__fmul_rn(p, m),  1.4249322787E-1f);
    p = __fadd_rn(__fmul_rn(p, m), -1.6668057665E-1f);
    p = __fadd_rn(__fmul_rn(p, m),  2.0000714765E-1f);
    p = __fadd_rn(__fmul_rn(p, m), -2.4999993993E-1f);
    p = __fadd_rn(__fmul_rn(p, m),  3.3333331174E-1f);
    float y = __fmul_rn(m, __fmul_rn(z, p));
    float fe = (float)e;
    y = __fadd_rn(y, __fmul_rn(-2.12194440e-4f, fe));
    y = __fadd_rn(y, __fmul_rn(-0.5f, z));
    float rr = __fadd_rn(m, y);
    rr = __fadd_rn(rr, __fmul_rn(0.693359375f, fe));
    return rr;
}

__device__ __forceinline__ float log1p_xla(float x){
    float u = __fadd_rn(x, 1.0f);
    if (u == 1.0f) return x;
    float lu = log_xla(u);
    float um1 = __fsub_rn(u, 1.0f);
    return __fmul_rn(lu, __fdiv_rn(x, um1));
}

__device__ __forceinline__ float logaddexp_x(float x, float y){
    float amax = fmaxf(x, y);
    float d = __fsub_rn(x, y);
    float e = exp_xla(-fabsf(d));
    float l1p = log1p_xla(e);
    return __fadd_rn(amax, l1p);
}

// monotone float -> uint (ascending); no NaN/-0 candidates by construction
__device__ __forceinline__ unsigned ford(float f){
    unsigned u = __float_as_uint(f);
    return (u & 0x80000000u) ? ~u : (u | 0x80000000u);
}

// ---------------- f64-packed selection keys (candidate idx, 11 bits) ----------------
// bits = (ford(sc)<<31) | ((~idx & 0x7FF)<<20): positive normal f64 for all
// reachable scores -> f64 order == u64 order == (score, ~idx) lexicographic.
__device__ __forceinline__ double packkey(float sc, int k){
    u64 kb = ((u64)ford(sc) << 31) | ((u64)((~(u32)k) & 0x7FFu) << 20);
    return __longlong_as_double((long long)kb);
}
__device__ __forceinline__ int decodekey(double wk){
    u32 idxinv = (u32)((u64)__double_as_longlong(wk) >> 20) & 0x7FFu;
    return (int)((~idxinv) & 0x7FFu);
}
// lp-sort key: (ford(v)<<31) | ((~c & 0x7F)<<24); v recoverable from bits>>31.
__device__ __forceinline__ double packlp(float v, int c){
    u64 kb = ((u64)ford(v) << 31) | ((u64)((~(u32)c) & 0x7Fu) << 24);
    return __longlong_as_double((long long)kb);
}

// ---------------- intra-wave LDS fence ----------------
__device__ __forceinline__ void wave_fence(){
    asm volatile("s_waitcnt lgkmcnt(0)" ::: "memory");
    __builtin_amdgcn_sched_barrier(0);
}

// ---------------- all-DPP wave reduces ----------------
template<int CTRL>
__device__ __forceinline__ double dmaxd(double v){
    long long x = __double_as_longlong(v);
    int lo = __builtin_amdgcn_update_dpp((int)(u32)x, (int)(u32)x, CTRL, 0xF, 0xF, false);
    int hi = __builtin_amdgcn_update_dpp((int)(u32)(x >> 32), (int)(u32)(x >> 32), CTRL, 0xF, 0xF, false);
    double o = __longlong_as_double((long long)(((u64)(u32)hi << 32) | (u32)lo));
    return fmax(v, o);
}
// full 64-lane max (producer's lp sort; values on all lanes)
__device__ __forceinline__ double wave_maxd(double v){
    v = dmaxd<0xB1>(v); v = dmaxd<0x4E>(v); v = dmaxd<0x141>(v);
    v = dmaxd<0x140>(v); v = dmaxd<0x142>(v); v = dmaxd<0x143>(v);
    long long x = __double_as_longlong(v);
    u32 lo = (u32)__builtin_amdgcn_readlane((int)(u32)x, 63);
    u32 hi = (u32)__builtin_amdgcn_readlane((int)(u32)(x >> 32), 63);
    return __longlong_as_double((long long)(((u64)hi << 32) | lo));
}
// max over lanes 0..31 (lanes 32..63 hold 0-keys); 5 levels + readlane(31)
__device__ __forceinline__ double wave_maxd31(double v){
    v = dmaxd<0xB1>(v); v = dmaxd<0x4E>(v); v = dmaxd<0x141>(v);
    v = dmaxd<0x140>(v);
    v = dmaxd<0x142>(v);   // row_bcast15: lanes16-31 pick up max(0..15)
    long long x = __double_as_longlong(v);
    u32 lo = (u32)__builtin_amdgcn_readlane((int)(u32)x, 31);
    u32 hi = (u32)__builtin_amdgcn_readlane((int)(u32)(x >> 32), 31);
    return __longlong_as_double((long long)(((u64)hi << 32) | lo));
}
template<int CTRL>
__device__ __forceinline__ float dmaxf(float v){
    int o = __builtin_amdgcn_update_dpp(__float_as_int(v), __float_as_int(v), CTRL, 0xF, 0xF, false);
    return fmaxf(v, __int_as_float(o));
}
__device__ __forceinline__ float wave_maxf(float v){
    v = dmaxf<0xB1>(v); v = dmaxf<0x4E>(v); v = dmaxf<0x141>(v);
    v = dmaxf<0x140>(v); v = dmaxf<0x142>(v); v = dmaxf<0x143>(v);
    return __int_as_float(__builtin_amdgcn_readlane(__float_as_int(v), 63));
}

// ---------------- producer: bit-exact log-softmax + lp top-17 sort ----------------
__device__ __forceinline__ void produce_full(float x0, float x1v, float* __restrict__ dst,
                                             float2* __restrict__ srt, int lane,
                                             float* __restrict__ evS)
{
    float m = wave_maxf(fmaxf(x0, (lane < 32) ? x1v : -INFINITY));
    float sh0 = __fsub_rn(x0, m);
    float sh1 = 0.0f;
    evS[lane] = exp_xla(sh0);
    if (lane < 32){
        sh1 = __fsub_rn(x1v, m);
        evS[64 + lane] = exp_xla(sh1);
    }
    wave_fence();
    float ls = 0.0f;
    if (lane == 0){
        float s = 0.0f;                        // strict in-order reduce, init 0
        const float4* e4 = (const float4*)evS;
        #pragma unroll
        for (int g = 0; g < 24; ++g){
            float4 w = e4[g];
            s = __fadd_rn(s, w.x); s = __fadd_rn(s, w.y);
            s = __fadd_rn(s, w.z); s = __fadd_rn(s, w.w);
        }
        ls = log_xla(s);
    }
    ls = __int_as_float(__builtin_amdgcn_readlane(__float_as_int(ls), 0));
    float lp0 = __fsub_rn(sh0, ls);
    dst[lane] = lp0;
    float lp1 = 0.0f;
    if (lane < 32){
        lp1 = __fsub_rn(sh1, ls);
        dst[64 + lane] = lp1;
    }
    // ---- top-17 of the 95 non-blank lp (stable: ties -> ascending c) ----
    double k0 = packlp(lp0, lane);                               // c = lane (0..63)
    double k1 = (lane < 31) ? packlp(lp1, 64 + lane) : 0.0;      // c = 64..94; blank excluded
    double pl = fmax(k0, k1);
    #pragma unroll 1
    for (int i = 0; i < 17; ++i){
        double wk = wave_maxd(pl);
        if (lane == 0){
            u64 bits = (u64)__double_as_longlong(wk);
            int c = (int)((~(u32)(bits >> 24)) & 0x7Fu);
            u32 u = (u32)(bits >> 31);
            u32 vb = (u & 0x80000000u) ? (u ^ 0x80000000u) : ~u;  // ford^-1
            srt[i] = make_float2(__uint_as_float(vb), __int_as_float(c));
        }
        long long wkb = __double_as_longlong(wk);
        k0 = (__double_as_longlong(k0) == wkb) ? 0.0 : k0;
        k1 = (__double_as_longlong(k1) == wkb) ? 0.0 : k1;
        pl = fmax(k0, k1);
    }
}

__global__ __launch_bounds__(128)
void ctc_beam(const float* __restrict__ in, float* __restrict__ out)
{
    __shared__ __align__(16) float ring[2][VCLS];   // lp double buffer
    __shared__ __align__(8)  float2 srtS[2][17];    // sorted lp top-17 double buffer
    __shared__ __align__(16) float evS[VCLS];       // producer-private
    __shared__ float pbS[BWID], ptotS[BWID], npbS[BWID], staynbS[BWID];
    __shared__ int   lastS[BWID], lenS[BWID];
    __shared__ unsigned short bp[TSTEPS * BWID];    // backpointers: (parent<<8)|(char+1), 0 = stay
    __shared__ float finalsS[BWID];

    const int tid  = threadIdx.x;
    const int wid  = tid >> 6;                      // 0 = consumer, 1 = producer
    const int lane = tid & 63;
    const int b    = blockIdx.x;
    const int bm   = lane & 15;                     // beam id this lane mirrors
    const float* __restrict__ rowbase = in + (size_t)b * TSTEPS * VCLS;

    float pb_r = NEGF, pnb_r = NEGF;
    int last_r = -1, len_r = 0;

    float x0n = 0.f, x1n = 0.f;                     // producer row prefetch regs

    // ---- prologue ----
    if (wid == 1){
        x0n = rowbase[lane];
        x1n = (lane < 32) ? rowbase[64 + lane] : 0.f;
        produce_full(x0n, x1n, ring[0], srtS[0], lane, evS);
        // prefetch row 1
        x0n = rowbase[VCLS + lane];
        x1n = (lane < 32) ? rowbase[VCLS + 64 + lane] : 0.f;
    } else {
        pb_r = (bm == 0) ? 0.0f : NEGF;
        pnb_r = NEGF; last_r = -1; len_r = 0;
        if (lane < BWID){
            pbS[bm] = pb_r; lastS[bm] = -1; lenS[bm] = 0;
        }
    }
    __syncthreads();

    for (int t = 0; t < TSTEPS; ++t){
        if (wid == 1){
            if (t + 1 < TSTEPS){
                float cx0 = x0n, cx1 = x1n;
                if (t + 2 < TSTEPS){                 // prefetch row t+2 (hidden under produce)
                    x0n = rowbase[(size_t)(t + 2) * VCLS + lane];
                    x1n = (lane < 32) ? rowbase[(size_t)(t + 2) * VCLS + 64 + lane] : 0.f;
                }
                produce_full(cx0, cx1, ring[(t + 1) & 1], srtS[(t + 1) & 1], lane, evS);
            }
        } else {
            const float*  __restrict__ lpc = ring[t & 1];
            const float2* __restrict__ srt = srtS[t & 1];

            // ---- step 2: per-beam precompute (all lanes, for beam bm) ----
            float lpb = lpc[CCLS];
            float lpl = lpc[(last_r >= 0) ? last_r : 0];
            float pt  = logaddexp_x(pb_r, pnb_r);
            float npb = pt + lpb;
            float stnb = (last_r >= 0) ? (pnb_r + lpl) : NEGF;
            float stay = logaddexp_x(npb, stnb);
            if (lane < BWID){
                ptotS[bm] = pt; npbS[bm] = npb; staynbS[bm] = stnb;
            }

            // ---- build this beam's sorted ext stream st[0..15] (fused filter+insert) ----
            const int idx0 = BWID + bm * CCLS;
            double ins = (last_r >= 0) ? packkey(__fadd_rn(pb_r, lpl), idx0 + last_r) : 0.0;
            double st[16];
            {
                float2 e0 = srt[0];
                int c0 = __float_as_int(e0.y);
                double raw_c = packkey(__fadd_rn(pt, e0.x), idx0 + c0);
                bool seen = (c0 == last_r);
                bool gtprev = true;
                double flt_prev = 0.0;
                #pragma unroll
                for (int j = 0; j < 16; ++j){
                    float2 en = srt[j + 1];
                    int cn = __float_as_int(en.y);
                    double raw_n = packkey(__fadd_rn(pt, en.x), idx0 + cn);
                    double flt_j = seen ? raw_n : raw_c;         // filter out repeat char
                    bool gt = (flt_j > ins);
                    st[j] = gt ? flt_j : (gtprev ? ins : flt_prev);  // sorted insert of adjusted cand
                    gtprev = gt; flt_prev = flt_j;
                    raw_c = raw_n;
                    seen = seen | (cn == last_r);
                }
            }

            // ---- TIE REPAIR: lp-order != key-order only within equal-score runs
            // (bit-equal __fadd_rn(pt,lp) sums; order there is by ~idx). Two
            // sequential bubble passes sort any run of length <= 3 exactly. ----
            #pragma unroll
            for (int p = 0; p < 2; ++p){
                #pragma unroll
                for (int j = 0; j < 15; ++j){
                    double a = st[j], bb = st[j + 1];
                    bool sw = a < bb;
                    st[j]     = sw ? bb : a;
                    st[j + 1] = sw ? a : bb;
                }
            }

            // ---- heads: lanes 0-15 stay, 16-31 ext streams, 32-63 empty ----
            double head = (lane < 16) ? packkey(stay, bm)
                        : (lane < 32) ? st[0] : 0.0;

            // ---- 16 argmax rounds: 5-level DPP reduce + winner shift ----
            int mysel = 0;
            #pragma unroll 1
            for (int r = 0; r < BWID; ++r){
                double wk = wave_maxd31(head);
                int widx = decodekey(wk);
                if (bm == r) mysel = widx;
                if (r < BWID - 1){
                    bool win = (__double_as_longlong(head) == __double_as_longlong(wk));
                    #pragma unroll
                    for (int j = 0; j < 15; ++j) st[j] = win ? st[j + 1] : st[j];
                    st[15] = win ? 0.0 : st[15];
                    head = win ? ((lane >= 16) ? st[0] : 0.0) : head;
                }
            }

            // ---- step 5: new state for beam bm (all lanes mirror; lane<16 writes) ----
            wave_fence();                              // step-2 LDS writes -> cross-beam reads
            int nlast, nlen, parent, code;
            float npbV, npnbV;
            {
                int s = mysel;
                if (s < BWID){                         // stay
                    parent = s; code = 0;
                    nlast = lastS[s]; nlen = lenS[s];
                    npbV = npbS[s]; npnbV = staynbS[s];
                } else {                               // extend
                    u32 e = (u32)(s - BWID);
                    parent = (int)((e * 44151u) >> 22);        // exact e/95 for e<1520
                    int c = (int)(e - (u32)parent * 95u);
                    code = c + 1;
                    nlast = c; nlen = lenS[parent] + 1;
                    npbV = NEGF;
                    float bs = (c == lastS[parent]) ? pbS[parent] : ptotS[parent];
                    npnbV = __fadd_rn(bs, lpc[c]);
                }
            }
            wave_fence();                              // all reads done before writes
            pb_r = npbV; pnb_r = npnbV; last_r = nlast; len_r = nlen;
            if (lane < BWID){
                pbS[bm] = npbV; lastS[bm] = nlast; lenS[bm] = nlen;
                bp[t * BWID + bm] = (unsigned short)((parent << 8) | code);
            }
        }
        __syncthreads();
    }

    // ---- final: consumer wave only ----
    if (wid == 0){
        if (lane < BWID) finalsS[bm] = logaddexp_x(pb_r, pnb_r);
        wave_fence();
        int bi_loc = 0;
        if (lane == 0){
            float bv = finalsS[0];
            for (int i = 1; i < BWID; ++i){
                if (finalsS[i] > bv){ bv = finalsS[i]; bi_loc = i; }
            }
            out[(size_t)NBATCH * TSTEPS + b] = exp_xla(bv);   // probability
        }
        int bi = __builtin_amdgcn_readlane(bi_loc, 0);
        int L  = lenS[bi];
        for (int j = L + lane; j < TSTEPS; j += 64) out[(size_t)b * TSTEPS + j] = -1.0f;
        if (lane == 0){
            int beam = bi, pos = L;
            for (int t = TSTEPS - 1; t >= 0; --t){
                unsigned short e = bp[t * BWID + beam];
                int code = e & 0xFF;
                if (code){ out[(size_t)b * TSTEPS + (pos - 1)] = (float)(code - 1); pos--; }
                beam = e >> 8;
            }
        }
    }
}

extern "C" void kernel_launch(void* const* d_in, const int* in_sizes, int n_in,
                              void* d_out, int out_size, void* d_ws, size_t ws_size,
                              hipStream_t stream)
{
    const float* in = (const float*)d_in[0];
    float* out = (float*)d_out;
    hipLaunchKernelGGL(ctc_beam, dim3(NBATCH), dim3(128), 0, stream, in, out);
}

// Round 10
// 2477.462 us; speedup vs baseline: 2.7546x; 1.1734x over previous
//
#include <hip/hip_runtime.h>
#include <math.h>

// CTC prefix beam search, TWO examples per block (one per 32-lane half):
// wave0 = consumer (beam step, 2 examples), wave1 = producer (log-softmax +
// lp top-17 sort, 2 rows). B=512, T=512, V=96 (blank=95), W=16.
// Numerics replicate XLA:CPU f32 op-for-op (verified absmax 0.0 r3-r9).
// R10 = R9 + SIMD-packing: per-half DPP reduces (row_bcast15 row_mask=0xA,
// no bcast31) keep the halves independent; readlane(31)/(63) + select.
#define NBATCH 512
#define TSTEPS 512
#define VCLS   96
#define CCLS   95
#define BWID   16
#define NEGF   (-1e30f)

typedef unsigned long long u64;
typedef unsigned int u32;

// ---------------- XLA:CPU-replica transcendentals (no FMA, explicit rounding) ----------------
__device__ __forceinline__ float exp_xla(float x){
    x = fminf(x, 88.3762626647950f);
    x = fmaxf(x, -88.3762626647949f);
    float t = __fadd_rn(__fmul_rn(x, 1.44269504088896341f), 0.5f);
    float m = floorf(t);
    float r = __fadd_rn(__fmul_rn(m, -0.693359375f), x);
    r = __fadd_rn(__fmul_rn(m, 2.12194440e-4f), r);
    float y = 1.9875691500E-4f;
    y = __fadd_rn(__fmul_rn(y, r), 1.3981999507E-3f);
    y = __fadd_rn(__fmul_rn(y, r), 8.3334519073E-3f);
    y = __fadd_rn(__fmul_rn(y, r), 4.1665795894E-2f);
    y = __fadd_rn(__fmul_rn(y, r), 1.6666665459E-1f);
    y = __fadd_rn(__fmul_rn(y, r), 5.0000001201E-1f);
    float r2 = __fmul_rn(r, r);
    y = __fadd_rn(__fmul_rn(y, r2), r);
    y = __fadd_rn(y, 1.0f);
    int n = (int)m;
    unsigned sb = (unsigned)(n + 127);
    float s = __uint_as_float(sb << 23);
    return __fmul_rn(y, s);
}

__device__ __forceinline__ float log_xla(float x){
    unsigned bits = __float_as_uint(x);
    int e = (int)(bits >> 23) - 126;
    float m = __uint_as_float((bits & 0x007FFFFFu) | 0x3F000000u);
    if (m < 0.707106781186547524f){
        e -= 1;
        m = __fsub_rn(__fadd_rn(m, m), 1.0f);
    } else {
        m = __fsub_rn(m, 1.0f);
    }
    float z = __fmul_rn(m, m);
    float p = 7.0376836292E-2f;
    p = __fadd_rn(__fmul_rn(p, m), -1.1514610310E-1f);
    p = __fadd_rn(__fmul_rn(p, m),  1.1676998740E-1f);
    p = __fadd_rn(__fmul_rn(p, m), -1.2420140846E-1f);
    p = __fadd_rn(__fmul_rn(p, m),  1.4249322787E-1f);
    p = __fadd_rn(__fmul_rn(p, m), -1.6668057665E-1f);
    p = __fadd_rn(__fmul_rn(p, m),  2.0000714765E-1f);
    p = __fadd_rn(__fmul_rn(p, m), -2.4999993993E-1f);
    p = __fadd_rn(__fmul_rn(p, m),  3.3333331174E-1f);
    float y = __fmul_rn(m, __fmul_rn(z, p));
    float fe = (float)e;
    y = __fadd_rn(y, __fmul_rn(-2.12194440e-4f, fe));
    y = __fadd_rn(y, __fmul_rn(-0.5f, z));
    float rr = __fadd_rn(m, y);
    rr = __fadd_rn(rr, __fmul_rn(0.693359375f, fe));
    return rr;
}

__device__ __forceinline__ float log1p_xla(float x){
    float u = __fadd_rn(x, 1.0f);
    if (u == 1.0f) return x;
    float lu = log_xla(u);
    float um1 = __fsub_rn(u, 1.0f);
    return __fmul_rn(lu, __fdiv_rn(x, um1));
}

__device__ __forceinline__ float logaddexp_x(float x, float y){
    float amax = fmaxf(x, y);
    float d = __fsub_rn(x, y);
    float e = exp_xla(-fabsf(d));
    float l1p = log1p_xla(e);
    return __fadd_rn(amax, l1p);
}

// monotone float -> uint (ascending); no NaN/-0 candidates by construction
__device__ __forceinline__ unsigned ford(float f){
    unsigned u = __float_as_uint(f);
    return (u & 0x80000000u) ? ~u : (u | 0x80000000u);
}

// ---------------- f64-packed selection keys ----------------
__device__ __forceinline__ double packkey(float sc, int k){
    u64 kb = ((u64)ford(sc) << 31) | ((u64)((~(u32)k) & 0x7FFu) << 20);
    return __longlong_as_double((long long)kb);
}
__device__ __forceinline__ int decodekey(double wk){
    u32 idxinv = (u32)((u64)__double_as_longlong(wk) >> 20) & 0x7FFu;
    return (int)((~idxinv) & 0x7FFu);
}
__device__ __forceinline__ double packlp(float v, int c){
    u64 kb = ((u64)ford(v) << 31) | ((u64)((~(u32)c) & 0x7Fu) << 24);
    return __longlong_as_double((long long)kb);
}

// ---------------- intra-wave LDS fence ----------------
__device__ __forceinline__ void wave_fence(){
    asm volatile("s_waitcnt lgkmcnt(0)" ::: "memory");
    __builtin_amdgcn_sched_barrier(0);
}

// ---------------- per-half (32-lane) DPP max reduces ----------------
// Levels xor1,xor2,half_mirror,mirror stay inside 16-lane rows; row_bcast15
// with row_mask=0xA writes only rows 1,3 (row0.l15->row1, row2.l47->row3),
// never crossing the 32-lane half boundary. Then readlane(31)/(63) + select.
template<int CTRL, int RM>
__device__ __forceinline__ double dmaxd2(double v){
    long long x = __double_as_longlong(v);
    int lo = __builtin_amdgcn_update_dpp((int)(u32)x, (int)(u32)x, CTRL, RM, 0xF, false);
    int hi = __builtin_amdgcn_update_dpp((int)(u32)(x >> 32), (int)(u32)(x >> 32), CTRL, RM, 0xF, false);
    double o = __longlong_as_double((long long)(((u64)(u32)hi << 32) | (u32)lo));
    return fmax(v, o);
}
__device__ __forceinline__ double halfmax_sel(double v, int h){
    v = dmaxd2<0xB1, 0xF>(v);
    v = dmaxd2<0x4E, 0xF>(v);
    v = dmaxd2<0x141, 0xF>(v);
    v = dmaxd2<0x140, 0xF>(v);
    v = dmaxd2<0x142, 0xA>(v);
    long long x = __double_as_longlong(v);
    u32 lA = (u32)__builtin_amdgcn_readlane((int)(u32)x, 31);
    u32 hA = (u32)__builtin_amdgcn_readlane((int)(u32)(x >> 32), 31);
    u32 lB = (u32)__builtin_amdgcn_readlane((int)(u32)x, 63);
    u32 hB = (u32)__builtin_amdgcn_readlane((int)(u32)(x >> 32), 63);
    long long kA = (long long)(((u64)hA << 32) | lA);
    long long kB = (long long)(((u64)hB << 32) | lB);
    return __longlong_as_double(h ? kB : kA);
}
template<int CTRL, int RM>
__device__ __forceinline__ float dmaxf2(float v){
    int o = __builtin_amdgcn_update_dpp(__float_as_int(v), __float_as_int(v), CTRL, RM, 0xF, false);
    return fmaxf(v, __int_as_float(o));
}
__device__ __forceinline__ float halfmaxf_sel(float v, int h){
    v = dmaxf2<0xB1, 0xF>(v);
    v = dmaxf2<0x4E, 0xF>(v);
    v = dmaxf2<0x141, 0xF>(v);
    v = dmaxf2<0x140, 0xF>(v);
    v = dmaxf2<0x142, 0xA>(v);
    float a = __int_as_float(__builtin_amdgcn_readlane(__float_as_int(v), 31));
    float b = __int_as_float(__builtin_amdgcn_readlane(__float_as_int(v), 63));
    return h ? b : a;
}

// ---------------- producer: bit-exact log-softmax + lp top-17 sort (one row per half) ----------------
__device__ __forceinline__ void produce2(float xa, float xb, float xc,
                                         float* __restrict__ ringh, float2* __restrict__ srth,
                                         float* __restrict__ evh, int h, int l5)
{
    float m = halfmaxf_sel(fmaxf(fmaxf(xa, xb), xc), h);    // exact max over own row
    float sa = __fsub_rn(xa, m);
    float sb = __fsub_rn(xb, m);
    float sc = __fsub_rn(xc, m);
    evh[l5]      = exp_xla(sa);
    evh[32 + l5] = exp_xla(sb);
    evh[64 + l5] = exp_xla(sc);
    wave_fence();
    float ls = 0.0f;
    if (l5 == 0){                         // lanes 0 and 32 concurrently (own half)
        float s = 0.0f;                   // strict in-order reduce, init 0
        const float4* e4 = (const float4*)evh;
        #pragma unroll
        for (int g = 0; g < 24; ++g){
            float4 w = e4[g];
            s = __fadd_rn(s, w.x); s = __fadd_rn(s, w.y);
            s = __fadd_rn(s, w.z); s = __fadd_rn(s, w.w);
        }
        ls = log_xla(s);
    }
    {
        float lsA = __int_as_float(__builtin_amdgcn_readlane(__float_as_int(ls), 0));
        float lsB = __int_as_float(__builtin_amdgcn_readlane(__float_as_int(ls), 32));
        ls = h ? lsB : lsA;
    }
    float lp0 = __fsub_rn(sa, ls);
    float lp1 = __fsub_rn(sb, ls);
    float lp2 = __fsub_rn(sc, ls);
    ringh[l5]      = lp0;
    ringh[32 + l5] = lp1;
    ringh[64 + l5] = lp2;
    // ---- top-17 of the 95 non-blank lp (stable: ties -> ascending c) ----
    double k0 = packlp(lp0, l5);
    double k1 = packlp(lp1, 32 + l5);
    double k2 = (l5 < 31) ? packlp(lp2, 64 + l5) : 0.0;     // l5==31: c=95 blank, excluded
    double pl = fmax(fmax(k0, k1), k2);
    #pragma unroll 1
    for (int i = 0; i < 17; ++i){
        double wk = halfmax_sel(pl, h);
        if (l5 == 0){                     // lanes 0 / 32 write own half's srt
            u64 bits = (u64)__double_as_longlong(wk);
            int c = (int)((~(u32)(bits >> 24)) & 0x7Fu);
            u32 u = (u32)(bits >> 31);
            u32 vb = (u & 0x80000000u) ? (u ^ 0x80000000u) : ~u;  // ford^-1
            srth[i] = make_float2(__uint_as_float(vb), __int_as_float(c));
        }
        long long wkb = __double_as_longlong(wk);
        k0 = (__double_as_longlong(k0) == wkb) ? 0.0 : k0;
        k1 = (__double_as_longlong(k1) == wkb) ? 0.0 : k1;
        k2 = (__double_as_longlong(k2) == wkb) ? 0.0 : k2;
        pl = fmax(fmax(k0, k1), k2);
    }
}

__global__ __launch_bounds__(128)
void ctc_beam(const float* __restrict__ in, float* __restrict__ out)
{
    __shared__ __align__(16) float ring[2][2][VCLS];   // [buf][half][c]
    __shared__ __align__(8)  float2 srtS[2][2][17];    // [buf][half][rank]
    __shared__ __align__(16) float evS[2][VCLS];       // producer-private
    __shared__ float pbS[2][BWID], ptotS[2][BWID], npbS[2][BWID], staynbS[2][BWID];
    __shared__ int   lastS[2][BWID], lenS[2][BWID];
    __shared__ unsigned short bp[2][TSTEPS][BWID];     // backpointers (32 KB)
    __shared__ float finalsS[2][BWID];

    const int tid  = threadIdx.x;
    const int wid  = tid >> 6;                      // 0 = consumer, 1 = producer
    const int lane = tid & 63;
    const int h    = lane >> 5;                     // example half (0 = A, 1 = B)
    const int l5   = lane & 31;
    const int bm   = lane & 15;                     // beam id this lane mirrors
    const int bex  = blockIdx.x * 2 + h;            // this half's example index
    const float* __restrict__ rowbase = in + (size_t)bex * TSTEPS * VCLS;

    float pb_r = NEGF, pnb_r = NEGF;
    int last_r = -1, len_r = 0;

    float xa = 0.f, xb = 0.f, xc = 0.f;             // producer row prefetch regs

    // ---- prologue ----
    if (wid == 1){
        xa = rowbase[l5]; xb = rowbase[32 + l5]; xc = rowbase[64 + l5];
        produce2(xa, xb, xc, ring[0][h], srtS[0][h], evS[h], h, l5);
        xa = rowbase[VCLS + l5]; xb = rowbase[VCLS + 32 + l5]; xc = rowbase[VCLS + 64 + l5];
    } else {
        pb_r = (bm == 0) ? 0.0f : NEGF;
        pnb_r = NEGF; last_r = -1; len_r = 0;
        if (l5 < BWID){
            pbS[h][bm] = pb_r; lastS[h][bm] = -1; lenS[h][bm] = 0;
        }
    }
    __syncthreads();

    for (int t = 0; t < TSTEPS; ++t){
        if (wid == 1){
            if (t + 1 < TSTEPS){
                float cxa = xa, cxb = xb, cxc = xc;
                if (t + 2 < TSTEPS){                // prefetch row t+2 (hidden under produce)
                    const float* r2 = rowbase + (size_t)(t + 2) * VCLS;
                    xa = r2[l5]; xb = r2[32 + l5]; xc = r2[64 + l5];
                }
                produce2(cxa, cxb, cxc, ring[(t + 1) & 1][h], srtS[(t + 1) & 1][h], evS[h], h, l5);
            }
        } else {
            const float*  __restrict__ lpc = ring[t & 1][h];
            const float2* __restrict__ srt = srtS[t & 1][h];

            // ---- step 2: per-beam precompute (all lanes, for beam bm of own half) ----
            float lpb = lpc[CCLS];
            float lpl = lpc[(last_r >= 0) ? last_r : 0];
            float pt  = logaddexp_x(pb_r, pnb_r);
            float npb = pt + lpb;
            float stnb = (last_r >= 0) ? (pnb_r + lpl) : NEGF;
            float stay = logaddexp_x(npb, stnb);
            if (l5 < BWID){
                ptotS[h][bm] = pt; npbS[h][bm] = npb; staynbS[h][bm] = stnb;
            }

            // ---- build this beam's sorted ext stream st[0..15] (fused filter+insert) ----
            const int idx0 = BWID + bm * CCLS;
            double ins = (last_r >= 0) ? packkey(__fadd_rn(pb_r, lpl), idx0 + last_r) : 0.0;
            double st[16];
            {
                float2 e0 = srt[0];
                int c0 = __float_as_int(e0.y);
                double raw_c = packkey(__fadd_rn(pt, e0.x), idx0 + c0);
                bool seen = (c0 == last_r);
                bool gtprev = true;
                double flt_prev = 0.0;
                #pragma unroll
                for (int j = 0; j < 16; ++j){
                    float2 en = srt[j + 1];
                    int cn = __float_as_int(en.y);
                    double raw_n = packkey(__fadd_rn(pt, en.x), idx0 + cn);
                    double flt_j = seen ? raw_n : raw_c;         // filter out repeat char
                    bool gt = (flt_j > ins);
                    st[j] = gt ? flt_j : (gtprev ? ins : flt_prev);  // sorted insert
                    gtprev = gt; flt_prev = flt_j;
                    raw_c = raw_n;
                    seen = seen | (cn == last_r);
                }
            }

            // ---- TIE REPAIR: bit-equal sums order by ~idx; 2 bubble passes ----
            #pragma unroll
            for (int p = 0; p < 2; ++p){
                #pragma unroll
                for (int j = 0; j < 15; ++j){
                    double a = st[j], bbk = st[j + 1];
                    bool sw = a < bbk;
                    st[j]     = sw ? bbk : a;
                    st[j + 1] = sw ? a : bbk;
                }
            }

            // ---- heads: (lane&31)<16 stay, else ext stream; both halves full ----
            double head = (l5 < BWID) ? packkey(stay, bm) : st[0];

            // ---- 16 argmax rounds: per-half 5-level DPP reduce + winner shift ----
            int mysel = 0;
            #pragma unroll 1
            for (int r = 0; r < BWID; ++r){
                double wk = halfmax_sel(head, h);     // own half's global max
                int widx = decodekey(wk);
                if (bm == r) mysel = widx;
                if (r < BWID - 1){
                    bool win = (__double_as_longlong(head) == __double_as_longlong(wk));
                    #pragma unroll
                    for (int j = 0; j < 15; ++j) st[j] = win ? st[j + 1] : st[j];
                    st[15] = win ? 0.0 : st[15];
                    head = win ? ((l5 >= BWID) ? st[0] : 0.0) : head;
                }
            }

            // ---- step 5: new state for beam bm of own half ----
            wave_fence();                              // step-2 LDS writes -> cross-beam reads
            int nlast, nlen, parent, code;
            float npbV, npnbV;
            {
                int s = mysel;
                if (s < BWID){                         // stay
                    parent = s; code = 0;
                    nlast = lastS[h][s]; nlen = lenS[h][s];
                    npbV = npbS[h][s]; npnbV = staynbS[h][s];
                } else {                               // extend
                    u32 e = (u32)(s - BWID);
                    parent = (int)((e * 44151u) >> 22);        // exact e/95 for e<1520
                    int c = (int)(e - (u32)parent * 95u);
                    code = c + 1;
                    nlast = c; nlen = lenS[h][parent] + 1;
                    npbV = NEGF;
                    float bs = (c == lastS[h][parent]) ? pbS[h][parent] : ptotS[h][parent];
                    npnbV = __fadd_rn(bs, lpc[c]);
                }
            }
            wave_fence();                              // all reads done before writes
            pb_r = npbV; pnb_r = npnbV; last_r = nlast; len_r = nlen;
            if (l5 < BWID){
                pbS[h][bm] = npbV; lastS[h][bm] = nlast; lenS[h][bm] = nlen;
                bp[h][t][bm] = (unsigned short)((parent << 8) | code);
            }
        }
        __syncthreads();
    }

    // ---- final: consumer wave only (two examples concurrently) ----
    if (wid == 0){
        if (l5 < BWID) finalsS[h][bm] = logaddexp_x(pb_r, pnb_r);
        wave_fence();
        int bi_loc = 0;
        if (l5 == 0){                                  // lanes 0 and 32
            float bv = finalsS[h][0];
            for (int i = 1; i < BWID; ++i){
                if (finalsS[h][i] > bv){ bv = finalsS[h][i]; bi_loc = i; }
            }
            out[(size_t)NBATCH * TSTEPS + bex] = exp_xla(bv);   // probability
        }
        int biA = __builtin_amdgcn_readlane(bi_loc, 0);
        int biB = __builtin_amdgcn_readlane(bi_loc, 32);
        int bi = h ? biB : biA;
        int L  = lenS[h][bi];
        for (int j = L + l5; j < TSTEPS; j += 32) out[(size_t)bex * TSTEPS + j] = -1.0f;
        if (l5 == 0){                                  // lanes 0 and 32 trace own half
            int beam = bi, pos = L;
            for (int t = TSTEPS - 1; t >= 0; --t){
                unsigned short e = bp[h][t][beam];
                int code = e & 0xFF;
                if (code){ out[(size_t)bex * TSTEPS + (pos - 1)] = (float)(code - 1); pos--; }
                beam = e >> 8;
            }
        }
    }
}

extern "C" void kernel_launch(void* const* d_in, const int* in_sizes, int n_in,
                              void* d_out, int out_size, void* d_ws, size_t ws_size,
                              hipStream_t stream)
{
    const float* in = (const float*)d_in[0];
    float* out = (float*)d_out;
    hipLaunchKernelGGL(ctc_beam, dim3(NBATCH / 2), dim3(128), 0, stream, in, out);
}

// Round 13
// 2427.284 us; speedup vs baseline: 2.8115x; 1.0207x over previous
//
#include <hip/hip_runtime.h>
#include <math.h>

// CTC prefix beam search, TWO examples per block, INTERLEAVED-row layout:
// example eh=0 owns rows 0,2 (lanes 0-15,32-47), eh=1 owns rows 1,3.
// wave0 = consumer (beam steps), wave1 = producer (log-softmax + lp top-17).
// B=512, T=512, V=96 (blank=95), W=16.
// Numerics replicate XLA:CPU f32 op-for-op (verified absmax 0.0 r3-r10).
// R13 = R12 with the cross-32 combine replaced by __shfl_xor(v,32,64) —
// verified semantics (R5 kernel passed with it); permlane32_swap abandoned
// (unverifiable operand semantics, 2 failed rounds with identical absmax).
#define NBATCH 512
#define TSTEPS 512
#define VCLS   96
#define CCLS   95
#define BWID   16
#define NEGF   (-1e30f)

typedef unsigned long long u64;
typedef unsigned int u32;

// ---------------- XLA:CPU-replica transcendentals (no FMA, explicit rounding) ----------------
__device__ __forceinline__ float exp_xla(float x){
    x = fminf(x, 88.3762626647950f);
    x = fmaxf(x, -88.3762626647949f);
    float t = __fadd_rn(__fmul_rn(x, 1.44269504088896341f), 0.5f);
    float m = floorf(t);
    float r = __fadd_rn(__fmul_rn(m, -0.693359375f), x);
    r = __fadd_rn(__fmul_rn(m, 2.12194440e-4f), r);
    float y = 1.9875691500E-4f;
    y = __fadd_rn(__fmul_rn(y, r), 1.3981999507E-3f);
    y = __fadd_rn(__fmul_rn(y, r), 8.3334519073E-3f);
    y = __fadd_rn(__fmul_rn(y, r), 4.1665795894E-2f);
    y = __fadd_rn(__fmul_rn(y, r), 1.6666665459E-1f);
    y = __fadd_rn(__fmul_rn(y, r), 5.0000001201E-1f);
    float r2 = __fmul_rn(r, r);
    y = __fadd_rn(__fmul_rn(y, r2), r);
    y = __fadd_rn(y, 1.0f);
    int n = (int)m;
    unsigned sb = (unsigned)(n + 127);
    float s = __uint_as_float(sb << 23);
    return __fmul_rn(y, s);
}

__device__ __forceinline__ float log_xla(float x){
    unsigned bits = __float_as_uint(x);
    int e = (int)(bits >> 23) - 126;
    float m = __uint_as_float((bits & 0x007FFFFFu) | 0x3F000000u);
    if (m < 0.707106781186547524f){
        e -= 1;
        m = __fsub_rn(__fadd_rn(m, m), 1.0f);
    } else {
        m = __fsub_rn(m, 1.0f);
    }
    float z = __fmul_rn(m, m);
    float p = 7.0376836292E-2f;
    p = __fadd_rn(__fmul_rn(p, m), -1.1514610310E-1f);
    p = __fadd_rn(__fmul_rn(p, m),  1.1676998740E-1f);
    p = __fadd_rn(__fmul_rn(p, m), -1.2420140846E-1f);
    p = __fadd_rn(__fmul_rn(p, m),  1.4249322787E-1f);
    p = __fadd_rn(__fmul_rn(p, m), -1.6668057665E-1f);
    p = __fadd_rn(__fmul_rn(p, m),  2.0000714765E-1f);
    p = __fadd_rn(__fmul_rn(p, m), -2.4999993993E-1f);
    p = __fadd_rn(__fmul_rn(p, m),  3.3333331174E-1f);
    float y = __fmul_rn(m, __fmul_rn(z, p));
    float fe = (float)e;
    y = __fadd_rn(y, __fmul_rn(-2.12194440e-4f, fe));
    y = __fadd_rn(y, __fmul_rn(-0.5f, z));
    float rr = __fadd_rn(m, y);
    rr = __fadd_rn(rr, __fmul_rn(0.693359375f, fe));
    return rr;
}

__device__ __forceinline__ float log1p_xla(float x){
    float u = __fadd_rn(x, 1.0f);
    if (u == 1.0f) return x;
    float lu = log_xla(u);
    float um1 = __fsub_rn(u, 1.0f);
    return __fmul_rn(lu, __fdiv_rn(x, um1));
}

__device__ __forceinline__ float logaddexp_x(float x, float y){
    float amax = fmaxf(x, y);
    float d = __fsub_rn(x, y);
    float e = exp_xla(-fabsf(d));
    float l1p = log1p_xla(e);
    return __fadd_rn(amax, l1p);
}

// monotone float -> uint (ascending); no NaN/-0 candidates by construction
__device__ __forceinline__ unsigned ford(float f){
    unsigned u = __float_as_uint(f);
    return (u & 0x80000000u) ? ~u : (u | 0x80000000u);
}

// ---------------- f64-packed selection keys ----------------
__device__ __forceinline__ double packkey(float sc, int k){
    u64 kb = ((u64)ford(sc) << 31) | ((u64)((~(u32)k) & 0x7FFu) << 20);
    return __longlong_as_double((long long)kb);
}
__device__ __forceinline__ int decodekey(double wk){
    u32 idxinv = (u32)((u64)__double_as_longlong(wk) >> 20) & 0x7FFu;
    return (int)((~idxinv) & 0x7FFu);
}
__device__ __forceinline__ double packlp(float v, int c){
    u64 kb = ((u64)ford(v) << 31) | ((u64)((~(u32)c) & 0x7Fu) << 24);
    return __longlong_as_double((long long)kb);
}

// ---------------- intra-wave LDS fence ----------------
__device__ __forceinline__ void wave_fence(){
    asm volatile("s_waitcnt lgkmcnt(0)" ::: "memory");
    __builtin_amdgcn_sched_barrier(0);
}

// ---------------- all-lane per-example max reduces (interleaved layout) ----------------
// rows {0,2} = example 0, rows {1,3} = example 1. Butterfly: xor1, xor2 (quad
// perms), row_half_mirror, row_mirror -> row-uniform (rows of 16); then one
// __shfl_xor(32) pairs lane i with i^32 = row r with r^2 (same example).
// Every lane ends with its example's max; no readlane, no select.
template<int CTRL>
__device__ __forceinline__ double dmaxd(double v){
    long long x = __double_as_longlong(v);
    int lo = __builtin_amdgcn_update_dpp((int)(u32)x, (int)(u32)x, CTRL, 0xF, 0xF, false);
    int hi = __builtin_amdgcn_update_dpp((int)(u32)(x >> 32), (int)(u32)(x >> 32), CTRL, 0xF, 0xF, false);
    double o = __longlong_as_double((long long)(((u64)(u32)hi << 32) | (u32)lo));
    return fmax(v, o);
}
template<int CTRL>
__device__ __forceinline__ float dmaxf(float v){
    int o = __builtin_amdgcn_update_dpp(__float_as_int(v), __float_as_int(v), CTRL, 0xF, 0xF, false);
    return fmaxf(v, __int_as_float(o));
}
__device__ __forceinline__ double exmax_d(double v){
    v = dmaxd<0xB1>(v);    // quad_perm xor1
    v = dmaxd<0x4E>(v);    // quad_perm xor2
    v = dmaxd<0x141>(v);   // row_half_mirror
    v = dmaxd<0x140>(v);   // row_mirror -> row-uniform
    double o = __shfl_xor(v, 32, 64);   // row r <-> r^2 (same example)
    return fmax(v, o);
}
__device__ __forceinline__ float exmax_f(float v){
    v = dmaxf<0xB1>(v);
    v = dmaxf<0x4E>(v);
    v = dmaxf<0x141>(v);
    v = dmaxf<0x140>(v);
    float o = __shfl_xor(v, 32, 64);
    return fmaxf(v, o);
}

// ---------------- producer: bit-exact log-softmax + lp top-17 sort ----------------
__device__ __forceinline__ void produce2(float xa, float xb, float xc,
                                         float* __restrict__ ringh, float2* __restrict__ srth,
                                         float* __restrict__ evh, int vl, int eh)
{
    float m = exmax_f(fmaxf(fmaxf(xa, xb), xc));            // exact own-example max
    float sa = __fsub_rn(xa, m);
    float sb = __fsub_rn(xb, m);
    float sc = __fsub_rn(xc, m);
    evh[vl]      = exp_xla(sa);
    evh[32 + vl] = exp_xla(sb);
    evh[64 + vl] = exp_xla(sc);
    wave_fence();
    float ls = 0.0f;
    if (vl == 0){                          // lanes 0 (eh0) and 16 (eh1) concurrently
        float s = 0.0f;                    // strict in-order reduce, init 0
        const float4* e4 = (const float4*)evh;
        #pragma unroll
        for (int g = 0; g < 24; ++g){
            float4 w = e4[g];
            s = __fadd_rn(s, w.x); s = __fadd_rn(s, w.y);
            s = __fadd_rn(s, w.z); s = __fadd_rn(s, w.w);
        }
        ls = log_xla(s);
    }
    {
        float lsA = __int_as_float(__builtin_amdgcn_readlane(__float_as_int(ls), 0));
        float lsB = __int_as_float(__builtin_amdgcn_readlane(__float_as_int(ls), 16));
        ls = eh ? lsB : lsA;
    }
    float lp0 = __fsub_rn(sa, ls);
    float lp1 = __fsub_rn(sb, ls);
    float lp2 = __fsub_rn(sc, ls);
    ringh[vl]      = lp0;
    ringh[32 + vl] = lp1;
    ringh[64 + vl] = lp2;
    // ---- top-17 of the 95 non-blank lp (stable: ties -> ascending c) ----
    double k0 = packlp(lp0, vl);
    double k1 = packlp(lp1, 32 + vl);
    double k2 = (vl < 31) ? packlp(lp2, 64 + vl) : 0.0;      // vl==31: c=95 blank, excluded
    double pl = fmax(fmax(k0, k1), k2);
    #pragma unroll 1
    for (int i = 0; i < 17; ++i){
        double wk = exmax_d(pl);
        if (vl == 0){
            u64 bits = (u64)__double_as_longlong(wk);
            int c = (int)((~(u32)(bits >> 24)) & 0x7Fu);
            u32 u = (u32)(bits >> 31);
            u32 vb = (u & 0x80000000u) ? (u ^ 0x80000000u) : ~u;  // ford^-1
            srth[i] = make_float2(__uint_as_float(vb), __int_as_float(c));
        }
        long long wkb = __double_as_longlong(wk);
        k0 = (__double_as_longlong(k0) == wkb) ? 0.0 : k0;
        k1 = (__double_as_longlong(k1) == wkb) ? 0.0 : k1;
        k2 = (__double_as_longlong(k2) == wkb) ? 0.0 : k2;
        pl = fmax(fmax(k0, k1), k2);
    }
}

__global__ __launch_bounds__(128)
void ctc_beam(const float* __restrict__ in, float* __restrict__ out)
{
    __shared__ __align__(16) float ring[4][2][VCLS];   // [buf][ex][c] (2-step batching)
    __shared__ __align__(8)  float2 srtS[4][2][17];
    __shared__ __align__(16) float evS[2][VCLS];
    __shared__ float pbS[2][BWID], ptotS[2][BWID], npbS[2][BWID], staynbS[2][BWID];
    __shared__ int   lastS[2][BWID], lenS[2][BWID];
    __shared__ unsigned short bp[2][TSTEPS][BWID];     // backpointers (32 KB)
    __shared__ float finalsS[2][BWID];

    const int tid  = threadIdx.x;
    const int wid  = tid >> 6;                      // 0 = consumer, 1 = producer
    const int lane = tid & 63;
    const int eh   = (lane >> 4) & 1;               // example (rows 0,2 vs 1,3)
    const int vl   = ((lane >> 5) << 4) | (lane & 15);  // virtual lane in [0,32)
    const int bm   = lane & 15;
    const int bex  = blockIdx.x * 2 + eh;
    const float* __restrict__ rowbase = in + (size_t)bex * TSTEPS * VCLS;

    float pb_r = NEGF, pnb_r = NEGF;
    int last_r = -1, len_r = 0;

    float pa0 = 0.f, pb0 = 0.f, pc0 = 0.f, pa1 = 0.f, pb1 = 0.f, pc1 = 0.f;

    // ---- prologue ----
    if (wid == 1){
        float a0 = rowbase[vl], b0 = rowbase[32 + vl], c0 = rowbase[64 + vl];
        float a1 = rowbase[VCLS + vl], b1 = rowbase[VCLS + 32 + vl], c1 = rowbase[VCLS + 64 + vl];
        pa0 = rowbase[2 * VCLS + vl]; pb0 = rowbase[2 * VCLS + 32 + vl]; pc0 = rowbase[2 * VCLS + 64 + vl];
        pa1 = rowbase[3 * VCLS + vl]; pb1 = rowbase[3 * VCLS + 32 + vl]; pc1 = rowbase[3 * VCLS + 64 + vl];
        produce2(a0, b0, c0, ring[0][eh], srtS[0][eh], evS[eh], vl, eh);
        produce2(a1, b1, c1, ring[1][eh], srtS[1][eh], evS[eh], vl, eh);
    } else {
        pb_r = (bm == 0) ? 0.0f : NEGF;
        pnb_r = NEGF; last_r = -1; len_r = 0;
        if (vl < BWID){
            pbS[eh][bm] = pb_r; lastS[eh][bm] = -1; lenS[eh][bm] = 0;
        }
    }
    __syncthreads();

    auto STEP = [&](int t){
        const float*  __restrict__ lpc = ring[t & 3][eh];
        const float2* __restrict__ srt = srtS[t & 3][eh];

        // ---- step 2: per-beam precompute (every lane, own (eh,bm)) ----
        float lpb = lpc[CCLS];
        float lpl = lpc[(last_r >= 0) ? last_r : 0];
        float pt  = logaddexp_x(pb_r, pnb_r);
        float npb = pt + lpb;
        float stnb = (last_r >= 0) ? (pnb_r + lpl) : NEGF;
        float stay = logaddexp_x(npb, stnb);
        if (vl < BWID){
            ptotS[eh][bm] = pt; npbS[eh][bm] = npb; staynbS[eh][bm] = stnb;
        }

        // ---- sorted ext stream st[0..15] (fused filter+insert) ----
        const int idx0 = BWID + bm * CCLS;
        double ins = (last_r >= 0) ? packkey(__fadd_rn(pb_r, lpl), idx0 + last_r) : 0.0;
        double st[16];
        {
            float2 e0 = srt[0];
            int c0 = __float_as_int(e0.y);
            double raw_c = packkey(__fadd_rn(pt, e0.x), idx0 + c0);
            bool seen = (c0 == last_r);
            bool gtprev = true;
            double flt_prev = 0.0;
            #pragma unroll
            for (int j = 0; j < 16; ++j){
                float2 en = srt[j + 1];
                int cn = __float_as_int(en.y);
                double raw_n = packkey(__fadd_rn(pt, en.x), idx0 + cn);
                double flt_j = seen ? raw_n : raw_c;         // filter out repeat char
                bool gt = (flt_j > ins);
                st[j] = gt ? flt_j : (gtprev ? ins : flt_prev);  // sorted insert
                gtprev = gt; flt_prev = flt_j;
                raw_c = raw_n;
                seen = seen | (cn == last_r);
            }
        }

        // ---- TIE REPAIR: bit-equal sums order by ~idx; 2 bubble passes ----
        #pragma unroll
        for (int p = 0; p < 2; ++p){
            #pragma unroll
            for (int j = 0; j < 15; ++j){
                double a = st[j], bk = st[j + 1];
                bool sw = a < bk;
                st[j]     = sw ? bk : a;
                st[j + 1] = sw ? a : bk;
            }
        }

        // ---- heads: vl<16 stay, vl>=16 ext stream ----
        double head = (vl < BWID) ? packkey(stay, bm) : st[0];

        // ---- 16 argmax rounds: all-lane butterfly, winner shift ----
        int mysel = 0;
        #pragma unroll 1
        for (int r = 0; r < BWID; ++r){
            double wk = exmax_d(head);             // own example's global max, every lane
            int widx = decodekey(wk);
            if (bm == r) mysel = widx;
            if (r < BWID - 1){
                bool win = (__double_as_longlong(head) == __double_as_longlong(wk));
                #pragma unroll
                for (int j = 0; j < 15; ++j) st[j] = win ? st[j + 1] : st[j];
                st[15] = win ? 0.0 : st[15];
                head = win ? ((vl >= BWID) ? st[0] : 0.0) : head;
            }
        }

        // ---- step 5: new state for own (eh,bm) ----
        wave_fence();                              // step-2 LDS writes -> cross-beam reads
        int nlast, nlen, parent, code;
        float npbV, npnbV;
        {
            int s = mysel;
            if (s < BWID){                         // stay
                parent = s; code = 0;
                nlast = lastS[eh][s]; nlen = lenS[eh][s];
                npbV = npbS[eh][s]; npnbV = staynbS[eh][s];
            } else {                               // extend
                u32 e = (u32)(s - BWID);
                parent = (int)((e * 44151u) >> 22);        // exact e/95 for e<1520
                int c = (int)(e - (u32)parent * 95u);
                code = c + 1;
                nlast = c; nlen = lenS[eh][parent] + 1;
                npbV = NEGF;
                float bs = (c == lastS[eh][parent]) ? pbS[eh][parent] : ptotS[eh][parent];
                npnbV = __fadd_rn(bs, lpc[c]);
            }
        }
        wave_fence();                              // all reads done before writes
        pb_r = npbV; pnb_r = npnbV; last_r = nlast; len_r = nlen;
        if (vl < BWID){
            pbS[eh][bm] = npbV; lastS[eh][bm] = nlast; lenS[eh][bm] = nlen;
            bp[eh][t][bm] = (unsigned short)((parent << 8) | code);
        }
    };

    for (int k = 0; k < TSTEPS / 2; ++k){
        if (wid == 1){
            if (k + 1 < TSTEPS / 2){
                float a0 = pa0, b0 = pb0, c0 = pc0, a1 = pa1, b1 = pb1, c1 = pc1;
                if (k + 2 < TSTEPS / 2){           // prefetch rows 2k+4, 2k+5
                    const float* r4 = rowbase + (size_t)(2 * k + 4) * VCLS;
                    pa0 = r4[vl]; pb0 = r4[32 + vl]; pc0 = r4[64 + vl];
                    pa1 = r4[VCLS + vl]; pb1 = r4[VCLS + 32 + vl]; pc1 = r4[VCLS + 64 + vl];
                }
                produce2(a0, b0, c0, ring[(2 * k + 2) & 3][eh], srtS[(2 * k + 2) & 3][eh], evS[eh], vl, eh);
                produce2(a1, b1, c1, ring[(2 * k + 3) & 3][eh], srtS[(2 * k + 3) & 3][eh], evS[eh], vl, eh);
            }
        } else {
            STEP(2 * k);
            STEP(2 * k + 1);
        }
        __syncthreads();
    }

    // ---- final: consumer wave only (two examples concurrently) ----
    if (wid == 0){
        if (vl < BWID) finalsS[eh][bm] = logaddexp_x(pb_r, pnb_r);
        wave_fence();
        int bi_loc = 0;
        if (vl == 0){                              // lanes 0 (eh0) and 16 (eh1)
            float bv = finalsS[eh][0];
            for (int i = 1; i < BWID; ++i){
                if (finalsS[eh][i] > bv){ bv = finalsS[eh][i]; bi_loc = i; }
            }
            out[(size_t)NBATCH * TSTEPS + bex] = exp_xla(bv);   // probability
        }
        int biA = __builtin_amdgcn_readlane(bi_loc, 0);
        int biB = __builtin_amdgcn_readlane(bi_loc, 16);
        int bi = eh ? biB : biA;
        int L  = lenS[eh][bi];
        for (int j = L + vl; j < TSTEPS; j += 32) out[(size_t)bex * TSTEPS + j] = -1.0f;
        if (vl == 0){
            int beam = bi, pos = L;
            for (int t = TSTEPS - 1; t >= 0; --t){
                unsigned short e = bp[eh][t][beam];
                int code = e & 0xFF;
                if (code){ out[(size_t)bex * TSTEPS + (pos - 1)] = (float)(code - 1); pos--; }
                beam = e >> 8;
            }
        }
    }
}

extern "C" void kernel_launch(void* const* d_in, const int* in_sizes, int n_in,
                              void* d_out, int out_size, void* d_ws, size_t ws_size,
                              hipStream_t stream)
{
    const float* in = (const float*)d_in[0];
    float* out = (float*)d_out;
    hipLaunchKernelGGL(ctc_beam, dim3(NBATCH / 2), dim3(128), 0, stream, in, out);
}

// Round 16
// 2113.550 us; speedup vs baseline: 3.2289x; 1.1484x over previous
//
#include <hip/hip_runtime.h>
#include <math.h>

// CTC prefix beam search, TWO examples per block, 16-LANE-ROW layout:
// consumer wave: example eh = (lane>>4)&1 on its 16-lane row; stay candidate
// and sorted ext stream CO-LOCATED per lane -> all reduces are 4 row-local
// DPP levels (no cross-row ops at all). Producer wave: 4 units (ex x row)
// computed concurrently in one call. B=512, T=512, V=96 (blank=95), W=16.
// Numerics replicate XLA:CPU f32 op-for-op (verified absmax 0.0 r3-r13).
#define NBATCH 512
#define TSTEPS 512
#define VCLS   96
#define CCLS   95
#define BWID   16
#define NEGF   (-1e30f)

typedef unsigned long long u64;
typedef unsigned int u32;

// ---------------- XLA:CPU-replica transcendentals (no FMA, explicit rounding) ----------------
__device__ __forceinline__ float exp_xla(float x){
    x = fminf(x, 88.3762626647950f);
    x = fmaxf(x, -88.3762626647949f);
    float t = __fadd_rn(__fmul_rn(x, 1.44269504088896341f), 0.5f);
    float m = floorf(t);
    float r = __fadd_rn(__fmul_rn(m, -0.693359375f), x);
    r = __fadd_rn(__fmul_rn(m, 2.12194440e-4f), r);
    float y = 1.9875691500E-4f;
    y = __fadd_rn(__fmul_rn(y, r), 1.3981999507E-3f);
    y = __fadd_rn(__fmul_rn(y, r), 8.3334519073E-3f);
    y = __fadd_rn(__fmul_rn(y, r), 4.1665795894E-2f);
    y = __fadd_rn(__fmul_rn(y, r), 1.6666665459E-1f);
    y = __fadd_rn(__fmul_rn(y, r), 5.0000001201E-1f);
    float r2 = __fmul_rn(r, r);
    y = __fadd_rn(__fmul_rn(y, r2), r);
    y = __fadd_rn(y, 1.0f);
    int n = (int)m;
    unsigned sb = (unsigned)(n + 127);
    float s = __uint_as_float(sb << 23);
    return __fmul_rn(y, s);
}

__device__ __forceinline__ float log_xla(float x){
    unsigned bits = __float_as_uint(x);
    int e = (int)(bits >> 23) - 126;
    float m = __uint_as_float((bits & 0x007FFFFFu) | 0x3F000000u);
    if (m < 0.707106781186547524f){
        e -= 1;
        m = __fsub_rn(__fadd_rn(m, m), 1.0f);
    } else {
        m = __fsub_rn(m, 1.0f);
    }
    float z = __fmul_rn(m, m);
    float p = 7.0376836292E-2f;
    p = __fadd_rn(__fmul_rn(p, m), -1.1514610310E-1f);
    p = __fadd_rn(__fmul_rn(p, m),  1.1676998740E-1f);
    p = __fadd_rn(__fmul_rn(p, m), -1.2420140846E-1f);
    p = __fadd_rn(__fmul_rn(p, m),  1.4249322787E-1f);
    p = __fadd_rn(__fmul_rn(p, m), -1.6668057665E-1f);
    p = __fadd_rn(__fmul_rn(p, m),  2.0000714765E-1f);
    p = __fadd_rn(__fmul_rn(p, m), -2.4999993993E-1f);
    p = __fadd_rn(__fmul_rn(p, m),  3.3333331174E-1f);
    float y = __fmul_rn(m, __fmul_rn(z, p));
    float fe = (float)e;
    y = __fadd_rn(y, __fmul_rn(-2.12194440e-4f, fe));
    y = __fadd_rn(y, __fmul_rn(-0.5f, z));
    float rr = __fadd_rn(m, y);
    rr = __fadd_rn(rr, __fmul_rn(0.693359375f, fe));
    return rr;
}

__device__ __forceinline__ float log1p_xla(float x){
    float u = __fadd_rn(x, 1.0f);
    if (u == 1.0f) return x;
    float lu = log_xla(u);
    float um1 = __fsub_rn(u, 1.0f);
    return __fmul_rn(lu, __fdiv_rn(x, um1));
}

__device__ __forceinline__ float logaddexp_x(float x, float y){
    float amax = fmaxf(x, y);
    float d = __fsub_rn(x, y);
    float e = exp_xla(-fabsf(d));
    float l1p = log1p_xla(e);
    return __fadd_rn(amax, l1p);
}

// monotone float -> uint (ascending); no NaN/-0 candidates by construction
__device__ __forceinline__ unsigned ford(float f){
    unsigned u = __float_as_uint(f);
    return (u & 0x80000000u) ? ~u : (u | 0x80000000u);
}

// ---------------- f64-packed selection keys ----------------
__device__ __forceinline__ double packkey(float sc, int k){
    u64 kb = ((u64)ford(sc) << 31) | ((u64)((~(u32)k) & 0x7FFu) << 20);
    return __longlong_as_double((long long)kb);
}
__device__ __forceinline__ int decodekey(double wk){
    u32 idxinv = (u32)((u64)__double_as_longlong(wk) >> 20) & 0x7FFu;
    return (int)((~idxinv) & 0x7FFu);
}
__device__ __forceinline__ double packlp(float v, int c){
    u64 kb = ((u64)ford(v) << 31) | ((u64)((~(u32)c) & 0x7Fu) << 24);
    return __longlong_as_double((long long)kb);
}

// ---------------- intra-wave LDS fence ----------------
__device__ __forceinline__ void wave_fence(){
    asm volatile("s_waitcnt lgkmcnt(0)" ::: "memory");
    __builtin_amdgcn_sched_barrier(0);
}

// ---------------- row-local (16-lane) max reduces: 4 DPP levels, pure VALU ----------------
template<int CTRL>
__device__ __forceinline__ double dmaxd(double v){
    long long x = __double_as_longlong(v);
    int lo = __builtin_amdgcn_update_dpp((int)(u32)x, (int)(u32)x, CTRL, 0xF, 0xF, false);
    int hi = __builtin_amdgcn_update_dpp((int)(u32)(x >> 32), (int)(u32)(x >> 32), CTRL, 0xF, 0xF, false);
    double o = __longlong_as_double((long long)(((u64)(u32)hi << 32) | (u32)lo));
    return fmax(v, o);
}
template<int CTRL>
__device__ __forceinline__ float dmaxf(float v){
    int o = __builtin_amdgcn_update_dpp(__float_as_int(v), __float_as_int(v), CTRL, 0xF, 0xF, false);
    return fmaxf(v, __int_as_float(o));
}
__device__ __forceinline__ double rowmax_d(double v){
    v = dmaxd<0xB1>(v);    // quad_perm xor1
    v = dmaxd<0x4E>(v);    // quad_perm xor2
    v = dmaxd<0x141>(v);   // row_half_mirror (cross 4-groups in 8)
    v = dmaxd<0x140>(v);   // row_mirror (cross 8-groups in 16) -> row-uniform
    return v;
}
__device__ __forceinline__ float rowmax_f(float v){
    v = dmaxf<0xB1>(v);
    v = dmaxf<0x4E>(v);
    v = dmaxf<0x141>(v);
    v = dmaxf<0x140>(v);
    return v;
}

__global__ __launch_bounds__(128)
void ctc_beam(const float* __restrict__ in, float* __restrict__ out)
{
    __shared__ __align__(16) float ring[4][2][VCLS];   // [buf][ex][c]
    __shared__ __align__(8)  float2 srtS[4][2][17];    // [buf][ex][rank]
    __shared__ __align__(16) float evS[4][VCLS];       // [unit][c] producer-private
    __shared__ float lsS[4];
    __shared__ float pbS[2][BWID], ptotS[2][BWID], npbS[2][BWID], staynbS[2][BWID];
    __shared__ int   lastS[2][BWID], lenS[2][BWID];
    __shared__ unsigned short bp[2][TSTEPS][BWID];     // backpointers (32 KB)
    __shared__ float finalsS[2][BWID];

    const int tid  = threadIdx.x;
    const int wid  = tid >> 6;                      // 0 = consumer, 1 = producer
    const int lane = tid & 63;
    const int rl   = lane & 15;                     // lane within 16-lane row
    const int eh   = (lane >> 4) & 1;               // consumer example (dup on lanes 32-63)
    const int bm   = rl;                            // beam this lane owns
    const int unit = lane >> 4;                     // producer unit 0..3
    const int pex  = unit & 1;                      // unit's example
    const int pdt  = unit >> 1;                     // unit's row offset (0 or 1)
    const int bex  = blockIdx.x * 2 + eh;
    const int pbex = blockIdx.x * 2 + pex;
    const float* __restrict__ prow = in + (size_t)pbex * TSTEPS * VCLS;

    float pb_r = NEGF, pnb_r = NEGF;
    int last_r = -1, len_r = 0;

    float xv[6];                                    // producer prefetch regs

    // ---- producer: one call computes rows (2k+2+pdt) for both examples (4 units) ----
    auto LOADROW = [&](int r, float* dst){
        const float* p = prow + (size_t)r * VCLS + rl;
        #pragma unroll
        for (int j = 0; j < 6; ++j) dst[j] = p[j * 16];
    };
    auto PRODUCE = [&](int buf, const float* x){
        float lm = fmaxf(fmaxf(fmaxf(x[0], x[1]), fmaxf(x[2], x[3])), fmaxf(x[4], x[5]));
        float m = rowmax_f(lm);                      // exact own-row max
        float sh[6];
        #pragma unroll
        for (int j = 0; j < 6; ++j){
            sh[j] = __fsub_rn(x[j], m);
            evS[unit][j * 16 + rl] = exp_xla(sh[j]);
        }
        wave_fence();
        if (rl == 0){                                // lanes 0,16,32,48: 4 parallel chains
            float s = 0.0f;                          // strict in-order reduce, init 0
            const float4* e4 = (const float4*)evS[unit];
            #pragma unroll
            for (int g = 0; g < 24; ++g){
                float4 w = e4[g];
                s = __fadd_rn(s, w.x); s = __fadd_rn(s, w.y);
                s = __fadd_rn(s, w.z); s = __fadd_rn(s, w.w);
            }
            lsS[unit] = log_xla(s);
        }
        wave_fence();
        float ls = lsS[unit];
        double kk[6];
        #pragma unroll
        for (int j = 0; j < 6; ++j){
            float lp = __fsub_rn(sh[j], ls);
            ring[buf][pex][j * 16 + rl] = lp;
            int c = j * 16 + rl;
            kk[j] = (c == CCLS) ? 0.0 : packlp(lp, c);   // blank excluded
        }
        double t0 = fmax(kk[0], kk[1]), t1 = fmax(kk[2], kk[3]), t2 = fmax(kk[4], kk[5]);
        double pl = fmax(fmax(t0, t1), t2);
        #pragma unroll 1
        for (int i = 0; i < 17; ++i){                // top-17, stable (ties -> ascending c)
            double wk = rowmax_d(pl);
            if (rl == 0){
                u64 bits = (u64)__double_as_longlong(wk);
                int c = (int)((~(u32)(bits >> 24)) & 0x7Fu);
                u32 u = (u32)(bits >> 31);
                u32 vb = (u & 0x80000000u) ? (u ^ 0x80000000u) : ~u;  // ford^-1
                srtS[buf][pex][i] = make_float2(__uint_as_float(vb), __int_as_float(c));
            }
            long long wkb = __double_as_longlong(wk);
            #pragma unroll
            for (int j = 0; j < 6; ++j)
                kk[j] = (__double_as_longlong(kk[j]) == wkb) ? 0.0 : kk[j];
            double u0 = fmax(kk[0], kk[1]), u1 = fmax(kk[2], kk[3]), u2 = fmax(kk[4], kk[5]);
            pl = fmax(fmax(u0, u1), u2);
        }
    };

    // ---- prologue ----
    if (wid == 1){
        LOADROW(pdt, xv);
        PRODUCE(pdt, xv);                            // rows 0,1 for both examples
        LOADROW(2 + pdt, xv);                        // prefetch rows 2,3
    } else {
        pb_r = (bm == 0) ? 0.0f : NEGF;
        pnb_r = NEGF; last_r = -1; len_r = 0;
        if (lane < 32){
            pbS[eh][bm] = pb_r; lastS[eh][bm] = -1; lenS[eh][bm] = 0;
        }
    }
    __syncthreads();

    auto STEP = [&](int t){
        const float*  __restrict__ lpc = ring[t & 3][eh];
        const float2* __restrict__ srt = srtS[t & 3][eh];

        // ---- step 2: per-beam precompute (every lane, own (eh,bm)) ----
        float lpb = lpc[CCLS];
        float lpl = lpc[(last_r >= 0) ? last_r : 0];
        float pt  = logaddexp_x(pb_r, pnb_r);
        float npb = pt + lpb;
        float stnb = (last_r >= 0) ? (pnb_r + lpl) : NEGF;
        float stay = logaddexp_x(npb, stnb);
        if (lane < 32){
            ptotS[eh][bm] = pt; npbS[eh][bm] = npb; staynbS[eh][bm] = stnb;
        }

        // ---- sorted ext stream st[0..15] (fused filter+insert) ----
        const int idx0 = BWID + bm * CCLS;
        double ins = (last_r >= 0) ? packkey(__fadd_rn(pb_r, lpl), idx0 + last_r) : 0.0;
        double st[16];
        {
            float2 e0 = srt[0];
            int c0 = __float_as_int(e0.y);
            double raw_c = packkey(__fadd_rn(pt, e0.x), idx0 + c0);
            bool seen = (c0 == last_r);
            bool gtprev = true;
            double flt_prev = 0.0;
            #pragma unroll
            for (int j = 0; j < 16; ++j){
                float2 en = srt[j + 1];
                int cn = __float_as_int(en.y);
                double raw_n = packkey(__fadd_rn(pt, en.x), idx0 + cn);
                double flt_j = seen ? raw_n : raw_c;         // filter out repeat char
                bool gt = (flt_j > ins);
                st[j] = gt ? flt_j : (gtprev ? ins : flt_prev);  // sorted insert
                gtprev = gt; flt_prev = flt_j;
                raw_c = raw_n;
                seen = seen | (cn == last_r);
            }
        }

        // ---- TIE REPAIR: bit-equal sums order by ~idx; 2 bubble passes ----
        #pragma unroll
        for (int p = 0; p < 2; ++p){
            #pragma unroll
            for (int j = 0; j < 15; ++j){
                double a = st[j], bk = st[j + 1];
                bool sw = a < bk;
                st[j]     = sw ? bk : a;
                st[j + 1] = sw ? a : bk;
            }
        }

        // ---- 16 argmax rounds: stay+stream co-located, 4-level row reduce ----
        double stay_k = packkey(stay, bm);
        int mysel = 0;
        #pragma unroll 1
        for (int r = 0; r < BWID; ++r){
            double loc = fmax(stay_k, st[0]);
            double wk = rowmax_d(loc);             // own example's global max, every lane
            if (bm == r) mysel = decodekey(wk);
            if (r < BWID - 1){
                long long wkb = __double_as_longlong(wk);
                bool winstay = (__double_as_longlong(stay_k) == wkb);
                bool winst   = (__double_as_longlong(st[0]) == wkb);
                stay_k = winstay ? 0.0 : stay_k;
                #pragma unroll
                for (int j = 0; j < 15; ++j) st[j] = winst ? st[j + 1] : st[j];
                st[15] = winst ? 0.0 : st[15];
            }
        }

        // ---- step 5: new state for own (eh,bm) ----
        wave_fence();                              // step-2 LDS writes -> cross-beam reads
        int nlast, nlen, parent, code;
        float npbV, npnbV;
        {
            int s = mysel;
            if (s < BWID){                         // stay
                parent = s; code = 0;
                nlast = lastS[eh][s]; nlen = lenS[eh][s];
                npbV = npbS[eh][s]; npnbV = staynbS[eh][s];
            } else {                               // extend
                u32 e = (u32)(s - BWID);
                parent = (int)((e * 44151u) >> 22);        // exact e/95 for e<1520
                int c = (int)(e - (u32)parent * 95u);
                code = c + 1;
                nlast = c; nlen = lenS[eh][parent] + 1;
                npbV = NEGF;
                float bs = (c == lastS[eh][parent]) ? pbS[eh][parent] : ptotS[eh][parent];
                npnbV = __fadd_rn(bs, lpc[c]);
            }
        }
        wave_fence();                              // all reads done before writes
        pb_r = npbV; pnb_r = npnbV; last_r = nlast; len_r = nlen;
        if (lane < 32){
            pbS[eh][bm] = npbV; lastS[eh][bm] = nlast; lenS[eh][bm] = nlen;
            bp[eh][t][bm] = (unsigned short)((parent << 8) | code);
        }
    };

    for (int k = 0; k < TSTEPS / 2; ++k){
        if (wid == 1){
            if (k + 1 < TSTEPS / 2){
                float cx[6];
                #pragma unroll
                for (int j = 0; j < 6; ++j) cx[j] = xv[j];
                if (k + 2 < TSTEPS / 2)
                    LOADROW(2 * k + 4 + pdt, xv);  // prefetch next pair
                PRODUCE((2 * k + 2 + pdt) & 3, cx);
            }
        } else {
            STEP(2 * k);
            STEP(2 * k + 1);
        }
        __syncthreads();
    }

    // ---- final: consumer wave, lanes 0-31 ----
    if (wid == 0){
        if (lane < 32) finalsS[eh][bm] = logaddexp_x(pb_r, pnb_r);
        wave_fence();
        int bi_loc = 0;
        if (rl == 0 && lane < 32){                 // lanes 0 (eh0) and 16 (eh1)
            float bv = finalsS[eh][0];
            for (int i = 1; i < BWID; ++i){
                if (finalsS[eh][i] > bv){ bv = finalsS[eh][i]; bi_loc = i; }
            }
            out[(size_t)NBATCH * TSTEPS + bex] = exp_xla(bv);   // probability
        }
        int biA = __builtin_amdgcn_readlane(bi_loc, 0);
        int biB = __builtin_amdgcn_readlane(bi_loc, 16);
        int bi = eh ? biB : biA;
        int L  = lenS[eh][bi];
        if (lane < 32){
            for (int j = L + rl; j < TSTEPS; j += 16) out[(size_t)bex * TSTEPS + j] = -1.0f;
        }
        if (rl == 0 && lane < 32){
            int beam = bi, pos = L;
            for (int t = TSTEPS - 1; t >= 0; --t){
                unsigned short e = bp[eh][t][beam];
                int code = e & 0xFF;
                if (code){ out[(size_t)bex * TSTEPS + (pos - 1)] = (float)(code - 1); pos--; }
                beam = e >> 8;
            }
        }
    }
}

extern "C" void kernel_launch(void* const* d_in, const int* in_sizes, int n_in,
                              void* d_out, int out_size, void* d_ws, size_t ws_size,
                              hipStream_t stream)
{
    const float* in = (const float*)d_in[0];
    float* out = (float*)d_out;
    hipLaunchKernelGGL(ctc_beam, dim3(NBATCH / 2), dim3(128), 0, stream, in, out);
}

// Round 19
// 1640.803 us; speedup vs baseline: 4.1592x; 1.2881x over previous
//
#include <hip/hip_runtime.h>
#include <math.h>

// CTC prefix beam search, TWO examples per block, 16-LANE-ROW layout.
// R17 = R16 + instruction diet: bounded winner-shift (full-unroll rounds),
// extend-score decoded from winner key (state LDS = float2+int2), padded
// LDS rows (104) to kill 4-way bank aliasing, 4-step batching (ring[8]).
// Numerics replicate XLA:CPU f32 op-for-op (verified absmax 0.0 r3-r16).
#define NBATCH 512
#define TSTEPS 512
#define VCLS   96
#define CCLS   95
#define BWID   16
#define VPAD   104
#define NEGF   (-1e30f)

typedef unsigned long long u64;
typedef unsigned int u32;

// ---------------- XLA:CPU-replica transcendentals (no FMA, explicit rounding) ----------------
__device__ __forceinline__ float exp_xla(float x){
    x = fminf(x, 88.3762626647950f);
    x = fmaxf(x, -88.3762626647949f);
    float t = __fadd_rn(__fmul_rn(x, 1.44269504088896341f), 0.5f);
    float m = floorf(t);
    float r = __fadd_rn(__fmul_rn(m, -0.693359375f), x);
    r = __fadd_rn(__fmul_rn(m, 2.12194440e-4f), r);
    float y = 1.9875691500E-4f;
    y = __fadd_rn(__fmul_rn(y, r), 1.3981999507E-3f);
    y = __fadd_rn(__fmul_rn(y, r), 8.3334519073E-3f);
    y = __fadd_rn(__fmul_rn(y, r), 4.1665795894E-2f);
    y = __fadd_rn(__fmul_rn(y, r), 1.6666665459E-1f);
    y = __fadd_rn(__fmul_rn(y, r), 5.0000001201E-1f);
    float r2 = __fmul_rn(r, r);
    y = __fadd_rn(__fmul_rn(y, r2), r);
    y = __fadd_rn(y, 1.0f);
    int n = (int)m;
    unsigned sb = (unsigned)(n + 127);
    float s = __uint_as_float(sb << 23);
    return __fmul_rn(y, s);
}

__device__ __forceinline__ float log_xla(float x){
    unsigned bits = __float_as_uint(x);
    int e = (int)(bits >> 23) - 126;
    float m = __uint_as_float((bits & 0x007FFFFFu) | 0x3F000000u);
    if (m < 0.707106781186547524f){
        e -= 1;
        m = __fsub_rn(__fadd_rn(m, m), 1.0f);
    } else {
        m = __fsub_rn(m, 1.0f);
    }
    float z = __fmul_rn(m, m);
    float p = 7.0376836292E-2f;
    p = __fadd_rn(__fmul_rn(p, m), -1.1514610310E-1f);
    p = __fadd_rn(__fmul_rn(p, m),  1.1676998740E-1f);
    p = __fadd_rn(__fmul_rn(p, m), -1.2420140846E-1f);
    p = __fadd_rn(__fmul_rn(p, m),  1.4249322787E-1f);
    p = __fadd_rn(__fmul_rn(p, m), -1.6668057665E-1f);
    p = __fadd_rn(__fmul_rn(p, m),  2.0000714765E-1f);
    p = __fadd_rn(__fmul_rn(p, m), -2.4999993993E-1f);
    p = __fadd_rn(__fmul_rn(p, m),  3.3333331174E-1f);
    float y = __fmul_rn(m, __fmul_rn(z, p));
    float fe = (float)e;
    y = __fadd_rn(y, __fmul_rn(-2.12194440e-4f, fe));
    y = __fadd_rn(y, __fmul_rn(-0.5f, z));
    float rr = __fadd_rn(m, y);
    rr = __fadd_rn(rr, __fmul_rn(0.693359375f, fe));
    return rr;
}

__device__ __forceinline__ float log1p_xla(float x){
    float u = __fadd_rn(x, 1.0f);
    if (u == 1.0f) return x;
    float lu = log_xla(u);
    float um1 = __fsub_rn(u, 1.0f);
    return __fmul_rn(lu, __fdiv_rn(x, um1));
}

__device__ __forceinline__ float logaddexp_x(float x, float y){
    float amax = fmaxf(x, y);
    float d = __fsub_rn(x, y);
    float e = exp_xla(-fabsf(d));
    float l1p = log1p_xla(e);
    return __fadd_rn(amax, l1p);
}

// monotone float -> uint (ascending); no NaN/-0 candidates by construction
__device__ __forceinline__ unsigned ford(float f){
    unsigned u = __float_as_uint(f);
    return (u & 0x80000000u) ? ~u : (u | 0x80000000u);
}
__device__ __forceinline__ float unford(u32 u){
    return __uint_as_float((u & 0x80000000u) ? (u ^ 0x80000000u) : ~u);
}

// ---------------- f64-packed selection keys ----------------
__device__ __forceinline__ double packkey(float sc, int k){
    u64 kb = ((u64)ford(sc) << 31) | ((u64)((~(u32)k) & 0x7FFu) << 20);
    return __longlong_as_double((long long)kb);
}
__device__ __forceinline__ int decodekey(double wk){
    u32 idxinv = (u32)((u64)__double_as_longlong(wk) >> 20) & 0x7FFu;
    return (int)((~idxinv) & 0x7FFu);
}
__device__ __forceinline__ double packlp(float v, int c){
    u64 kb = ((u64)ford(v) << 31) | ((u64)((~(u32)c) & 0x7Fu) << 24);
    return __longlong_as_double((long long)kb);
}

// ---------------- intra-wave LDS fence ----------------
__device__ __forceinline__ void wave_fence(){
    asm volatile("s_waitcnt lgkmcnt(0)" ::: "memory");
    __builtin_amdgcn_sched_barrier(0);
}

// ---------------- row-local (16-lane) max reduces: 4 DPP levels, pure VALU ----------------
template<int CTRL>
__device__ __forceinline__ double dmaxd(double v){
    long long x = __double_as_longlong(v);
    int lo = __builtin_amdgcn_update_dpp((int)(u32)x, (int)(u32)x, CTRL, 0xF, 0xF, false);
    int hi = __builtin_amdgcn_update_dpp((int)(u32)(x >> 32), (int)(u32)(x >> 32), CTRL, 0xF, 0xF, false);
    double o = __longlong_as_double((long long)(((u64)(u32)hi << 32) | (u32)lo));
    return fmax(v, o);
}
template<int CTRL>
__device__ __forceinline__ float dmaxf(float v){
    int o = __builtin_amdgcn_update_dpp(__float_as_int(v), __float_as_int(v), CTRL, 0xF, 0xF, false);
    return fmaxf(v, __int_as_float(o));
}
__device__ __forceinline__ double rowmax_d(double v){
    v = dmaxd<0xB1>(v);    // quad_perm xor1
    v = dmaxd<0x4E>(v);    // quad_perm xor2
    v = dmaxd<0x141>(v);   // row_half_mirror
    v = dmaxd<0x140>(v);   // row_mirror -> row-uniform
    return v;
}
__device__ __forceinline__ float rowmax_f(float v){
    v = dmaxf<0xB1>(v);
    v = dmaxf<0x4E>(v);
    v = dmaxf<0x141>(v);
    v = dmaxf<0x140>(v);
    return v;
}

__global__ __launch_bounds__(128)
void ctc_beam(const float* __restrict__ in, float* __restrict__ out)
{
    __shared__ __align__(16) float ring[8][2][VPAD];   // [buf][ex][c] (4-step batching)
    __shared__ __align__(8)  float2 srtS[8][2][17];    // [buf][ex][rank]
    __shared__ __align__(16) float evS[4][VPAD];       // [unit][c] producer-private
    __shared__ float lsS[4];
    __shared__ float2 stateF2[2][BWID];                // {npb, staynb}
    __shared__ int2   lastlenS[2][BWID];               // {last, len}
    __shared__ unsigned short bp[2][TSTEPS][BWID];     // backpointers (32 KB)
    __shared__ float finalsS[2][BWID];

    const int tid  = threadIdx.x;
    const int wid  = tid >> 6;                      // 0 = consumer, 1 = producer
    const int lane = tid & 63;
    const int rl   = lane & 15;                     // lane within 16-lane row
    const int eh   = (lane >> 4) & 1;               // consumer example (dup on lanes 32-63)
    const int bm   = rl;                            // beam this lane owns
    const int unit = lane >> 4;                     // producer unit 0..3
    const int pex  = unit & 1;                      // unit's example
    const int pdt  = unit >> 1;                     // unit's row offset (0 or 1)
    const int bex  = blockIdx.x * 2 + eh;
    const int pbex = blockIdx.x * 2 + pex;
    const float* __restrict__ prow = in + (size_t)pbex * TSTEPS * VCLS;

    float pb_r = NEGF, pnb_r = NEGF;
    int last_r = -1, len_r = 0;

    float xv[6], xw[6];                             // producer prefetch regs (2 rows)

    auto LOADROW = [&](int r, float* dst){
        const float* p = prow + (size_t)r * VCLS + rl;
        #pragma unroll
        for (int j = 0; j < 6; ++j) dst[j] = p[j * 16];
    };
    // one call: log-softmax + lp top-17 sort for one row of each example (4 units)
    auto PRODUCE = [&](int buf, const float* x){
        float lm = fmaxf(fmaxf(fmaxf(x[0], x[1]), fmaxf(x[2], x[3])), fmaxf(x[4], x[5]));
        float m = rowmax_f(lm);                      // exact own-row max
        float sh[6];
        #pragma unroll
        for (int j = 0; j < 6; ++j){
            sh[j] = __fsub_rn(x[j], m);
            evS[unit][j * 16 + rl] = exp_xla(sh[j]);
        }
        wave_fence();
        if (rl == 0){                                // lanes 0,16,32,48: 4 parallel chains
            float s = 0.0f;                          // strict in-order reduce, init 0
            const float4* e4 = (const float4*)evS[unit];
            #pragma unroll
            for (int g = 0; g < 24; ++g){
                float4 w = e4[g];
                s = __fadd_rn(s, w.x); s = __fadd_rn(s, w.y);
                s = __fadd_rn(s, w.z); s = __fadd_rn(s, w.w);
            }
            lsS[unit] = log_xla(s);
        }
        wave_fence();
        float ls = lsS[unit];
        double kk[6];
        #pragma unroll
        for (int j = 0; j < 6; ++j){
            float lp = __fsub_rn(sh[j], ls);
            ring[buf][pex][j * 16 + rl] = lp;
            int c = j * 16 + rl;
            kk[j] = (c == CCLS) ? 0.0 : packlp(lp, c);   // blank excluded
        }
        double t0 = fmax(kk[0], kk[1]), t1 = fmax(kk[2], kk[3]), t2 = fmax(kk[4], kk[5]);
        double pl = fmax(fmax(t0, t1), t2);
        #pragma unroll 1
        for (int i = 0; i < 17; ++i){                // top-17, stable (ties -> ascending c)
            double wk = rowmax_d(pl);
            if (rl == 0){
                u64 bits = (u64)__double_as_longlong(wk);
                int c = (int)((~(u32)(bits >> 24)) & 0x7Fu);
                srtS[buf][pex][i] = make_float2(unford((u32)(bits >> 31)), __int_as_float(c));
            }
            long long wkb = __double_as_longlong(wk);
            #pragma unroll
            for (int j = 0; j < 6; ++j)
                kk[j] = (__double_as_longlong(kk[j]) == wkb) ? 0.0 : kk[j];
            double u0 = fmax(kk[0], kk[1]), u1 = fmax(kk[2], kk[3]), u2 = fmax(kk[4], kk[5]);
            pl = fmax(fmax(u0, u1), u2);
        }
    };

    // ---- prologue ----
    if (wid == 1){
        LOADROW(pdt, xv);
        PRODUCE(pdt, xv);                            // steps 0,1
        LOADROW(2 + pdt, xv);
        PRODUCE(2 + pdt, xv);                        // steps 2,3
        LOADROW(4 + pdt, xv);                        // prefetch steps 4,5
        LOADROW(6 + pdt, xw);                        // prefetch steps 6,7
    } else {
        pb_r = (bm == 0) ? 0.0f : NEGF;
        pnb_r = NEGF; last_r = -1; len_r = 0;
        if (lane < 32){
            lastlenS[eh][bm] = make_int2(-1, 0);
        }
    }
    __syncthreads();

    auto STEP = [&](int t){
        const float*  __restrict__ lpc = ring[t & 7][eh];
        const float2* __restrict__ srt = srtS[t & 7][eh];

        // ---- step 2: per-beam precompute (every lane, own (eh,bm)) ----
        float lpb = lpc[CCLS];
        float lpl = lpc[(last_r >= 0) ? last_r : 0];
        float pt  = logaddexp_x(pb_r, pnb_r);
        float npb = pt + lpb;
        float stnb = (last_r >= 0) ? (pnb_r + lpl) : NEGF;
        float stay = logaddexp_x(npb, stnb);
        if (lane < 32){
            stateF2[eh][bm] = make_float2(npb, stnb);
        }

        // ---- sorted ext stream st[0..15] (fused filter+insert) ----
        const int idx0 = BWID + bm * CCLS;
        double ins = (last_r >= 0) ? packkey(__fadd_rn(pb_r, lpl), idx0 + last_r) : 0.0;
        double st[16];
        {
            float2 e0 = srt[0];
            int c0 = __float_as_int(e0.y);
            double raw_c = packkey(__fadd_rn(pt, e0.x), idx0 + c0);
            bool seen = (c0 == last_r);
            bool gtprev = true;
            double flt_prev = 0.0;
            #pragma unroll
            for (int j = 0; j < 16; ++j){
                float2 en = srt[j + 1];
                int cn = __float_as_int(en.y);
                double raw_n = packkey(__fadd_rn(pt, en.x), idx0 + cn);
                double flt_j = seen ? raw_n : raw_c;         // filter out repeat char
                bool gt = (flt_j > ins);
                st[j] = gt ? flt_j : (gtprev ? ins : flt_prev);  // sorted insert
                gtprev = gt; flt_prev = flt_j;
                raw_c = raw_n;
                seen = seen | (cn == last_r);
            }
        }

        // ---- TIE REPAIR: bit-equal sums order by ~idx; 2 bubble passes ----
        #pragma unroll
        for (int p = 0; p < 2; ++p){
            #pragma unroll
            for (int j = 0; j < 15; ++j){
                double a = st[j], bk = st[j + 1];
                bool sw = a < bk;
                st[j]     = sw ? bk : a;
                st[j + 1] = sw ? a : bk;
            }
        }

        // ---- 16 argmax rounds, fully unrolled; shift bound shrinks with r ----
        double stay_k = packkey(stay, bm);
        int mysel = 0;
        float myscore = 0.0f;
        #pragma unroll
        for (int r = 0; r < BWID; ++r){
            double loc = fmax(stay_k, st[0]);
            double wk = rowmax_d(loc);             // own example's global max, every lane
            if (bm == r){
                mysel = decodekey(wk);
                myscore = unford((u32)((u64)__double_as_longlong(wk) >> 31));
            }
            if (r < BWID - 1){
                long long wkb = __double_as_longlong(wk);
                bool winstay = (__double_as_longlong(stay_k) == wkb);
                bool winst   = (__double_as_longlong(st[0]) == wkb);
                stay_k = winstay ? 0.0 : stay_k;
                // only depths 0..(15-r-1) can be consumed by the remaining rounds
                #pragma unroll
                for (int j = 0; j < BWID - 1 - r; ++j) st[j] = winst ? st[j + 1] : st[j];
            }
        }

        // ---- step 5: new state for own (eh,bm) ----
        wave_fence();                              // step-2 LDS writes -> cross-beam reads
        int nlast, nlen, parent, code;
        float npbV, npnbV;
        {
            int s = mysel;
            if (s < BWID){                         // stay
                parent = s; code = 0;
                float2 f2 = stateF2[eh][s];
                int2 i2 = lastlenS[eh][s];
                nlast = i2.x; nlen = i2.y;
                npbV = f2.x; npnbV = f2.y;
            } else {                               // extend: score comes from the key
                u32 e = (u32)(s - BWID);
                parent = (int)((e * 44151u) >> 22);        // exact e/95 for e<1520
                int c = (int)(e - (u32)parent * 95u);
                code = c + 1;
                nlast = c;
                int2 i2 = lastlenS[eh][parent];
                nlen = i2.y + 1;
                npbV = NEGF;
                npnbV = myscore;                   // == bs + lp[c], exact (from packed key)
            }
        }
        __builtin_amdgcn_sched_barrier(0);         // pin reads before the writes below
        pb_r = npbV; pnb_r = npnbV; last_r = nlast; len_r = nlen;
        if (lane < 32){
            lastlenS[eh][bm] = make_int2(nlast, nlen);
            bp[eh][t][bm] = (unsigned short)((parent << 8) | code);
        }
    };

    for (int k = 0; k < TSTEPS / 4; ++k){
        if (wid == 1){
            if (k + 1 < TSTEPS / 4){
                float cx[6], cy[6];
                #pragma unroll
                for (int j = 0; j < 6; ++j){ cx[j] = xv[j]; cy[j] = xw[j]; }
                if (k + 2 < TSTEPS / 4){           // prefetch batch k+1's rows
                    LOADROW(4 * k + 8 + pdt, xv);
                    LOADROW(4 * k + 10 + pdt, xw);
                }
                PRODUCE((4 * k + 4 + pdt) & 7, cx);
                PRODUCE((4 * k + 6 + pdt) & 7, cy);
            }
        } else {
            STEP(4 * k);
            STEP(4 * k + 1);
            STEP(4 * k + 2);
            STEP(4 * k + 3);
        }
        __syncthreads();
    }

    // ---- final: consumer wave, lanes 0-31 ----
    if (wid == 0){
        if (lane < 32) finalsS[eh][bm] = logaddexp_x(pb_r, pnb_r);
        wave_fence();
        int bi_loc = 0;
        if (rl == 0 && lane < 32){                 // lanes 0 (eh0) and 16 (eh1)
            float bv = finalsS[eh][0];
            for (int i = 1; i < BWID; ++i){
                if (finalsS[eh][i] > bv){ bv = finalsS[eh][i]; bi_loc = i; }
            }
            out[(size_t)NBATCH * TSTEPS + bex] = exp_xla(bv);   // probability
        }
        int biA = __builtin_amdgcn_readlane(bi_loc, 0);
        int biB = __builtin_amdgcn_readlane(bi_loc, 16);
        int bi = eh ? biB : biA;
        int L  = lastlenS[eh][bi].y;
        if (lane < 32){
            for (int j = L + rl; j < TSTEPS; j += 16) out[(size_t)bex * TSTEPS + j] = -1.0f;
        }
        if (rl == 0 && lane < 32){
            int beam = bi, pos = L;
            for (int t = TSTEPS - 1; t >= 0; --t){
                unsigned short e = bp[eh][t][beam];
                int code = e & 0xFF;
                if (code){ out[(size_t)bex * TSTEPS + (pos - 1)] = (float)(code - 1); pos--; }
                beam = e >> 8;
            }
        }
    }
}

extern "C" void kernel_launch(void* const* d_in, const int* in_sizes, int n_in,
                              void* d_out, int out_size, void* d_ws, size_t ws_size,
                              hipStream_t stream)
{
    const float* in = (const float*)d_in[0];
    float* out = (float*)d_out;
    hipLaunchKernelGGL(ctc_beam, dim3(NBATCH / 2), dim3(128), 0, stream, in, out);
}